// Round 7
// baseline (1167.047 us; speedup 1.0000x reference)
//
#include <hip/hip_runtime.h>
#include <hip/hip_fp16.h>

#define HH 4096
#define WW 4096

constexpr float C_LAM = 0.1f;   // ALPHA * LAMDA
constexpr float TAU_F = 0.25f;

// ---- first-iteration kernel geometry ----
#define BX 64
#define BY 8
#define VEC 4
#define TILE_W (BX * VEC)       // 256 cols per block

// ---- double-step kernel geometry ----
#define TW2 64                  // interior cols
#define TH2 32                  // interior rows
#define ERR 36                  // extended rows  [r0-2, r0+33]
#define ECC 72                  // extended cols  [c0-4, c0+67] (4-aligned)
#define NCH (ECC / 4)           // 18 chunks per row
#define NSL (ERR * NCH)         // 648 chunk-slots
#define LSZ (ERR * ECC)         // 2592 elements per LDS plane

union H2x4 { float4 f4; __half2 h2[4]; };
union H2x2 { float2 f2; __half2 h2[2]; };
union H2U  { __half2 h; unsigned int u; };

__device__ __forceinline__ float clip1(float v) {
    return fminf(1.0f, fmaxf(-1.0f, v));
}

// packed clamp to [-1,1] (no __hmax2/__hmin2 in ROCm 7.2 headers)
__device__ __forceinline__ __half2 clamp1h2(__half2 v) {
    H2U a; a.h = v;
    unsigned int lo = 0xBC00BC00u;   // (-1, -1) fp16
    unsigned int hi = 0x3C003C00u;   // (+1, +1) fp16
    unsigned int t, r;
    asm("v_pk_max_f16 %0, %1, %2" : "=v"(t) : "v"(a.u), "v"(lo));
    asm("v_pk_min_f16 %0, %1, %2" : "=v"(r) : "v"(t),   "v"(hi));
    H2U b; b.u = r;
    return b.h;
}

__device__ __forceinline__ __half2 shfl_up_h2(__half2 v) {
    H2U a; a.h = v;
    int s = __shfl_up((int)a.u, 1, 64);
    H2U b; b.u = (unsigned)s;
    return b.h;
}

// iteration 0 (p=0 -> u=x):  p = clip(tau * grad(x)); also emits x_h = fp16(x)
__global__ __launch_bounds__(512) void tv_first(const float* __restrict__ x,
                                                __half2* __restrict__ po,
                                                __half* __restrict__ xh)
{
    const int tx = threadIdx.x, ty = threadIdx.y;
    const int i = blockIdx.y * BY + ty;
    const int j = blockIdx.x * TILE_W + tx * VEC;
    const size_t idx = (size_t)i * WW + j;

    float4 xc4 = *(const float4*)(x + idx);
    float4 xd4 = make_float4(0.f, 0.f, 0.f, 0.f);
    if (i < HH - 1) xd4 = *(const float4*)(x + idx + WW);

    float c[4] = {xc4.x, xc4.y, xc4.z, xc4.w};
    float d[4] = {xd4.x, xd4.y, xd4.z, xd4.w};

    float xr = __shfl_down(c[0], 1, 64);
    if (tx == BX - 1 && j + VEC < WW) xr = x[idx + VEC];

    H2x4 o;
#pragma unroll
    for (int e = 0; e < 4; ++e) {
        float gx = (i < HH - 1) ? (d[e] - c[e]) : 0.f;
        float rn = (e < 3) ? c[e + 1] : xr;
        float gy = (j + e < WW - 1) ? (rn - c[e]) : 0.f;
        o.h2[e] = __floats2half2_rn(clip1(TAU_F * gx), clip1(TAU_F * gy));
    }
    *(float4*)(po + idx) = o.f4;

    H2x2 xs;
    xs.h2[0] = __floats2half2_rn(c[0], c[1]);
    xs.h2[1] = __floats2half2_rn(c[2], c[3]);
    *(float2*)(xh + idx) = xs.f2;
}

// -------- two fused Chambolle steps --------
// Neighbor access via wave shuffles (slots are wave-consecutive); only
// lane-edge threads fall back to exec-masked scalar LDS reads.
__global__ __launch_bounds__(256) void tv_iter2(const __half* __restrict__ xh,
                                                const __half2* __restrict__ pi,
                                                __half2* __restrict__ po)
{
    __shared__ __half2 sp0[LSZ];
    __shared__ __half2 sp1[LSZ];
    __shared__ float   su [LSZ];

    const int tid  = threadIdx.x;
    const int lane = tid & 63;
    const int r0 = blockIdx.y * TH2;
    const int c0 = blockIdx.x * TW2;
    const __half2 tau2 = __float2half2_rn(TAU_F);

    int lb[3], lup[3], llf[3], ldn[3], lrt[3], gj0a[3], gia[3], gofs[3];
    bool wr[3];
#pragma unroll
    for (int r = 0; r < 3; ++r) {
        int slot = tid + 256 * r;
        wr[r] = (slot < NSL);
        if (slot >= NSL) slot = NSL - 1;
        int cr = slot / NCH;
        int cc = slot - cr * NCH;
        int gi  = r0 - 2 + cr;
        int gj0 = c0 - 4 + cc * 4;
        int gic = min(max(gi, 0), HH - 1);
        int gjc = min(max(gj0, 0), WW - 4);
        gofs[r] = gic * WW + gjc;
        int l   = cr * ECC + cc * 4;
        lb[r]  = l;
        lup[r] = (cr > 0) ? l - ECC : l;
        llf[r] = (l > 0) ? l - 1 : 0;
        ldn[r] = (cr < ERR - 1) ? l + ECC : l;
        lrt[r] = min(l + 4, LSZ - 1);
        gj0a[r] = gj0;
        gia[r]  = gi;
    }

    // ---- stage A: load p0 + x chunks ----
    __half2 c2[3][4];
    H2x2    xc[3];
#pragma unroll
    for (int r = 0; r < 3; ++r) {
        H2x4 v; v.f4 = *(const float4*)(pi + gofs[r]);
        xc[r].f2    = *(const float2*)(xh + gofs[r]);
        if (wr[r]) *(float4*)&sp0[lb[r]] = v.f4;
        c2[r][0] = v.h2[0]; c2[r][1] = v.h2[1];
        c2[r][2] = v.h2[2]; c2[r][3] = v.h2[3];
    }
    __syncthreads();

    // ---- stage B: u1 = x - c*div(p0)  (dx auto-zero via clamped p0 copies) ----
    float u1v[3][4];
#pragma unroll
    for (int r = 0; r < 3; ++r) {
        H2x4 up; up.f4 = *(float4*)&sp0[lup[r]];
        __half2 lf = shfl_up_h2(c2[r][3]);
        if (lane == 0) lf = sp0[llf[r]];
        float xs[4] = {__low2float(xc[r].h2[0]), __high2float(xc[r].h2[0]),
                       __low2float(xc[r].h2[1]), __high2float(xc[r].h2[1])};
        float4 w;
        float* wp = &w.x;
#pragma unroll
        for (int e = 0; e < 4; ++e) {
            __half2 cc = c2[r][e];
            __half2 le = (e == 0) ? lf : c2[r][e - 1];
            float dx = __low2float(up.h2[e]) - __low2float(cc);
            float dy = __high2float(le) - __high2float(cc);
            dy = (gj0a[r] + e > 0) ? dy : 0.f;
            float u = xs[e] - C_LAM * (dx + dy);
            u1v[r][e] = u;
            wp[e] = u;
        }
        if (wr[r]) *(float4*)&su[lb[r]] = w;
    }
    __syncthreads();

    // ---- stage C: p1 = clip(p0 + tau*grad(u1)) (gx auto-zero at bottom) ----
    __half2 p1v[3][4];
#pragma unroll
    for (int r = 0; r < 3; ++r) {
        float4 dn4 = *(float4*)&su[ldn[r]];
        float urr = __shfl_down(u1v[r][0], 1, 64);
        if (lane == 63) urr = su[lrt[r]];
        float dn[4] = {dn4.x, dn4.y, dn4.z, dn4.w};
        H2x4 w;
#pragma unroll
        for (int e = 0; e < 4; ++e) {
            float uc = u1v[r][e];
            float gx = dn[e] - uc;
            float rt = (e == 3) ? urr : u1v[r][e + 1];
            float gy = (gj0a[r] + e < WW - 1) ? (rt - uc) : 0.f;
            __half2 g = __float22half2_rn(make_float2(gx, gy));
            __half2 p1 = clamp1h2(__hfma2(g, tau2, c2[r][e]));
            p1v[r][e] = p1;
            w.h2[e] = p1;
        }
        if (wr[r]) *(float4*)&sp1[lb[r]] = w.f4;
    }
    __syncthreads();

    // ---- stage D: u2 = u1 - c*div(p1 - p0)  (needs explicit gi>0 guard!) ----
#pragma unroll
    for (int r = 0; r < 3; ++r) {
        H2x4 a; a.f4 = *(float4*)&sp1[lup[r]];
        H2x4 b; b.f4 = *(float4*)&sp0[lup[r]];
        __half2 q[4];
#pragma unroll
        for (int e = 0; e < 4; ++e) q[e] = __hsub2(p1v[r][e], c2[r][e]);
        __half2 ql0 = shfl_up_h2(q[3]);
        if (lane == 0) ql0 = __hsub2(sp1[llf[r]], sp0[llf[r]]);
        float4 w;
        float* wp = &w.x;
#pragma unroll
        for (int e = 0; e < 4; ++e) {
            __half2 qu = __hsub2(a.h2[e], b.h2[e]);
            __half2 ql = (e == 0) ? ql0 : q[e - 1];
            float dx = __low2float(qu) - __low2float(q[e]);
            dx = (gia[r] > 0) ? dx : 0.f;
            float dy = __high2float(ql) - __high2float(q[e]);
            dy = (gj0a[r] + e > 0) ? dy : 0.f;
            float u2 = u1v[r][e] - C_LAM * (dx + dy);
            u1v[r][e] = u2;
            wp[e] = u2;
        }
        if (wr[r]) *(float4*)&su[lb[r]] = w;
    }
    __syncthreads();

    // ---- stage E: p2 = clip(p1 + tau*grad(u2)) on interior; write out ----
#pragma unroll
    for (int r = 0; r < 2; ++r) {
        int slot = tid + 256 * r;                   // < 512 exactly
        int ir = slot >> 4, icc = slot & 15;
        int er = ir + 2, ec = icc * 4 + 4;
        int l  = er * ECC + ec;
        int gi = r0 + ir, gj = c0 + icc * 4;

        float4 uc4 = *(float4*)&su[l];
        float4 ud4 = *(float4*)&su[l + ECC];
        H2x4 pp; pp.f4 = *(float4*)&sp1[l];
        float urr = __shfl_down(uc4.x, 1, 64);
        if ((tid & 15) == 15) urr = su[l + 4];
        float uc[4] = {uc4.x, uc4.y, uc4.z, uc4.w};
        float ud[4] = {ud4.x, ud4.y, ud4.z, ud4.w};

        H2x4 o;
#pragma unroll
        for (int e = 0; e < 4; ++e) {
            float gx = ud[e] - uc[e];
            gx = (gi < HH - 1) ? gx : 0.f;           // true-boundary guard
            float rt = (e == 3) ? urr : uc[e + 1];
            float gy = (gj + e < WW - 1) ? (rt - uc[e]) : 0.f;
            __half2 g = __float22half2_rn(make_float2(gx, gy));
            o.h2[e] = clamp1h2(__hfma2(g, tau2, pp.h2[e]));
        }
        *(float4*)(po + (size_t)gi * WW + gj) = o.f4;
    }
}

// -------- final: one more p-update (p49 -> p50) fused with the output --------
// stages A,B,C as in tv_iter2, then out = x_f32 - c*div(p50) from LDS.
__global__ __launch_bounds__(256) void tv_last(const __half* __restrict__ xh,
                                               const float* __restrict__ x,
                                               const __half2* __restrict__ pi,
                                               float* __restrict__ out)
{
    __shared__ __half2 sp0[LSZ];
    __shared__ __half2 sp1[LSZ];
    __shared__ float   su [LSZ];

    const int tid  = threadIdx.x;
    const int lane = tid & 63;
    const int r0 = blockIdx.y * TH2;
    const int c0 = blockIdx.x * TW2;
    const __half2 tau2 = __float2half2_rn(TAU_F);

    int lb[3], lup[3], llf[3], ldn[3], lrt[3], gj0a[3], gofs[3];
    bool wr[3];
#pragma unroll
    for (int r = 0; r < 3; ++r) {
        int slot = tid + 256 * r;
        wr[r] = (slot < NSL);
        if (slot >= NSL) slot = NSL - 1;
        int cr = slot / NCH;
        int cc = slot - cr * NCH;
        int gi  = r0 - 2 + cr;
        int gj0 = c0 - 4 + cc * 4;
        int gic = min(max(gi, 0), HH - 1);
        int gjc = min(max(gj0, 0), WW - 4);
        gofs[r] = gic * WW + gjc;
        int l   = cr * ECC + cc * 4;
        lb[r]  = l;
        lup[r] = (cr > 0) ? l - ECC : l;
        llf[r] = (l > 0) ? l - 1 : 0;
        ldn[r] = (cr < ERR - 1) ? l + ECC : l;
        lrt[r] = min(l + 4, LSZ - 1);
        gj0a[r] = gj0;
    }

    __half2 c2[3][4];
    H2x2    xc[3];
#pragma unroll
    for (int r = 0; r < 3; ++r) {
        H2x4 v; v.f4 = *(const float4*)(pi + gofs[r]);
        xc[r].f2    = *(const float2*)(xh + gofs[r]);
        if (wr[r]) *(float4*)&sp0[lb[r]] = v.f4;
        c2[r][0] = v.h2[0]; c2[r][1] = v.h2[1];
        c2[r][2] = v.h2[2]; c2[r][3] = v.h2[3];
    }
    __syncthreads();

    float u1v[3][4];
#pragma unroll
    for (int r = 0; r < 3; ++r) {
        H2x4 up; up.f4 = *(float4*)&sp0[lup[r]];
        __half2 lf = shfl_up_h2(c2[r][3]);
        if (lane == 0) lf = sp0[llf[r]];
        float xs[4] = {__low2float(xc[r].h2[0]), __high2float(xc[r].h2[0]),
                       __low2float(xc[r].h2[1]), __high2float(xc[r].h2[1])};
        float4 w;
        float* wp = &w.x;
#pragma unroll
        for (int e = 0; e < 4; ++e) {
            __half2 cc = c2[r][e];
            __half2 le = (e == 0) ? lf : c2[r][e - 1];
            float dx = __low2float(up.h2[e]) - __low2float(cc);
            float dy = __high2float(le) - __high2float(cc);
            dy = (gj0a[r] + e > 0) ? dy : 0.f;
            float u = xs[e] - C_LAM * (dx + dy);
            u1v[r][e] = u;
            wp[e] = u;
        }
        if (wr[r]) *(float4*)&su[lb[r]] = w;
    }
    __syncthreads();

#pragma unroll
    for (int r = 0; r < 3; ++r) {
        float4 dn4 = *(float4*)&su[ldn[r]];
        float urr = __shfl_down(u1v[r][0], 1, 64);
        if (lane == 63) urr = su[lrt[r]];
        float dn[4] = {dn4.x, dn4.y, dn4.z, dn4.w};
        H2x4 w;
#pragma unroll
        for (int e = 0; e < 4; ++e) {
            float uc = u1v[r][e];
            float gx = dn[e] - uc;
            float rt = (e == 3) ? urr : u1v[r][e + 1];
            float gy = (gj0a[r] + e < WW - 1) ? (rt - uc) : 0.f;
            __half2 g = __float22half2_rn(make_float2(gx, gy));
            w.h2[e] = clamp1h2(__hfma2(g, tau2, c2[r][e]));
        }
        if (wr[r]) *(float4*)&sp1[lb[r]] = w.f4;
    }
    __syncthreads();

    // ---- stage F: out = x - c*div(p50) on interior ----
#pragma unroll
    for (int r = 0; r < 2; ++r) {
        int slot = tid + 256 * r;
        int ir = slot >> 4, icc = slot & 15;
        int er = ir + 2, ec = icc * 4 + 4;
        int l  = er * ECC + ec;
        int gi = r0 + ir, gj = c0 + icc * 4;

        H2x4 pc_; pc_.f4 = *(float4*)&sp1[l];
        H2x4 pu_; pu_.f4 = *(float4*)&sp1[l - ECC];
        __half2 plf = shfl_up_h2(pc_.h2[3]);
        if ((tid & 15) == 0) plf = sp1[l - 1];

        float4 xr4 = *(const float4*)(x + (size_t)gi * WW + gj);
        float xv[4] = {xr4.x, xr4.y, xr4.z, xr4.w};
        float o[4];
#pragma unroll
        for (int e = 0; e < 4; ++e) {
            __half2 cc = pc_.h2[e];
            __half2 le = (e == 0) ? plf : pc_.h2[e - 1];
            float dx = __low2float(pu_.h2[e]) - __low2float(cc);
            dx = (gi > 0) ? dx : 0.f;
            float dy = __high2float(le) - __high2float(cc);
            dy = (gj + e > 0) ? dy : 0.f;
            o[e] = xv[e] - C_LAM * (dx + dy);
        }
        *(float4*)(out + (size_t)gi * WW + gj) = make_float4(o[0], o[1], o[2], o[3]);
    }
}

extern "C" void kernel_launch(void* const* d_in, const int* in_sizes, int n_in,
                              void* d_out, int out_size, void* d_ws, size_t ws_size,
                              hipStream_t stream)
{
    const float* x = (const float*)d_in[0];
    float* out = (float*)d_out;
    const size_t N = (size_t)HH * (size_t)WW;

    // ws layout: pA (64 MiB) | pB (64 MiB) | x_h (32 MiB)
    __half2* pA = (__half2*)d_ws;
    __half2* pB = pA + N;
    __half*  xh = (__half*)(pB + N);

    dim3 b1(BX, BY), g1(WW / TILE_W, HH / BY);
    dim3 b2(256), g2(WW / TW2, HH / TH2);

    tv_first<<<g1, b1, 0, stream>>>(x, pA, xh);              // iter 1
    __half2 *pin = pA, *pout = pB;
    for (int p = 0; p < 24; ++p) {                           // iters 2..49
        tv_iter2<<<g2, b2, 0, stream>>>(xh, pin, pout);
        __half2* t = pin; pin = pout; pout = t;
    }
    tv_last<<<g2, b2, 0, stream>>>(xh, x, pin, out);         // iter 50 + output
}

// Round 8
// 1091.353 us; speedup vs baseline: 1.0694x; 1.0694x over previous
//
#include <hip/hip_runtime.h>
#include <hip/hip_fp16.h>

#define HH 4096
#define WW 4096

constexpr float C_LAM = 0.1f;   // ALPHA * LAMDA
constexpr float TAU_F = 0.25f;

// ---- first-iteration kernel geometry ----
#define BX 64
#define BY 8
#define VEC 4
#define TILE_W (BX * VEC)       // 256 cols per block

// ---- tv_last (2-ring) geometry, from R7 ----
#define TW2 64
#define TH2 32
#define ERR 36
#define ECC 72
#define NCH (ECC / 4)
#define NSL (ERR * NCH)         // 648
#define LSZ (ERR * ECC)         // 2592

// ---- tv_iter3 (3-ring) geometry ----
#define ER3 38                  // rows [r0-3, r0+34]
#define EC3 72                  // cols [c0-4, c0+67], 4-aligned chunks
#define NCH3 (EC3 / 4)          // 18
#define NSL3 (ER3 * NCH3)       // 684 chunk-slots
#define LSZ3 (ER3 * EC3)        // 2736 elements per plane

union H2x4 { float4 f4; __half2 h2[4]; };
union H2x2 { float2 f2; __half2 h2[2]; };
union H2U  { __half2 h; unsigned int u; };

__device__ __forceinline__ float clip1(float v) {
    return fminf(1.0f, fmaxf(-1.0f, v));
}

// packed clamp to [-1,1] (no __hmax2/__hmin2 in ROCm 7.2 headers)
__device__ __forceinline__ __half2 clamp1h2(__half2 v) {
    H2U a; a.h = v;
    unsigned int lo = 0xBC00BC00u;   // (-1, -1) fp16
    unsigned int hi = 0x3C003C00u;   // (+1, +1) fp16
    unsigned int t, r;
    asm("v_pk_max_f16 %0, %1, %2" : "=v"(t) : "v"(a.u), "v"(lo));
    asm("v_pk_min_f16 %0, %1, %2" : "=v"(r) : "v"(t),   "v"(hi));
    H2U b; b.u = r;
    return b.h;
}

__device__ __forceinline__ __half2 shfl_up_h2(__half2 v) {
    H2U a; a.h = v;
    int s = __shfl_up((int)a.u, 1, 64);
    H2U b; b.u = (unsigned)s;
    return b.h;
}

// iteration 0 (p=0 -> u=x):  p = clip(tau * grad(x)); also emits x_h = fp16(x)
__global__ __launch_bounds__(512) void tv_first(const float* __restrict__ x,
                                                __half2* __restrict__ po,
                                                __half* __restrict__ xh)
{
    const int tx = threadIdx.x, ty = threadIdx.y;
    const int i = blockIdx.y * BY + ty;
    const int j = blockIdx.x * TILE_W + tx * VEC;
    const size_t idx = (size_t)i * WW + j;

    float4 xc4 = *(const float4*)(x + idx);
    float4 xd4 = make_float4(0.f, 0.f, 0.f, 0.f);
    if (i < HH - 1) xd4 = *(const float4*)(x + idx + WW);

    float c[4] = {xc4.x, xc4.y, xc4.z, xc4.w};
    float d[4] = {xd4.x, xd4.y, xd4.z, xd4.w};

    float xr = __shfl_down(c[0], 1, 64);
    if (tx == BX - 1 && j + VEC < WW) xr = x[idx + VEC];

    H2x4 o;
#pragma unroll
    for (int e = 0; e < 4; ++e) {
        float gx = (i < HH - 1) ? (d[e] - c[e]) : 0.f;
        float rn = (e < 3) ? c[e + 1] : xr;
        float gy = (j + e < WW - 1) ? (rn - c[e]) : 0.f;
        o.h2[e] = __floats2half2_rn(clip1(TAU_F * gx), clip1(TAU_F * gy));
    }
    *(float4*)(po + idx) = o.f4;

    H2x2 xs;
    xs.h2[0] = __floats2half2_rn(c[0], c[1]);
    xs.h2[1] = __floats2half2_rn(c[2], c[3]);
    *(float2*)(xh + idx) = xs.f2;
}

// -------- three fused Chambolle steps per pass --------
// u_s = xh - C*div(p_{s-1}) each sub-step (own chunk in regs; up/left via
// contiguous b128 neighbor-chunk reads). Guards at EVERY stage. Interior p3
// written straight from registers.
__global__ __launch_bounds__(256) void tv_iter3(const __half* __restrict__ xh,
                                                const __half2* __restrict__ pi,
                                                __half2* __restrict__ po)
{
    __shared__ __align__(16) __half2 sA[LSZ3];
    __shared__ __align__(16) __half2 sB[LSZ3];
    __shared__ __align__(16) float   sU[LSZ3];

    const int tid = threadIdx.x;
    const int r0 = blockIdx.y * TH2;
    const int c0 = blockIdx.x * TW2;
    const __half2 tau2 = __float2half2_rn(TAU_F);

    int lb[3], lup[3], llf[3], ldn[3], lrt[3], gj0a[3], gw[3];
    bool wr[3], wout[3], bdx[3], bgx[3];
    __half2 pc[3][4];
    float xf[3][4], uv[3][4];

#pragma unroll
    for (int r = 0; r < 3; ++r) {
        int slot = tid + 256 * r;
        wr[r] = (slot < NSL3);
        if (!wr[r]) slot = NSL3 - 1;           // dup slot: same data, writes masked
        int cr = slot / NCH3;
        int cc = slot - cr * NCH3;
        int gi  = r0 - 3 + cr;
        int gj0 = c0 - 4 + cc * 4;
        int gic = min(max(gi, 0), HH - 1);
        int gjc = min(max(gj0, 0), WW - 4);
        int gofs = gic * WW + gjc;
        int l = cr * EC3 + cc * 4;
        lb[r]  = l;
        lup[r] = (cr > 0)        ? l - EC3 : l;   // clamped: garbage-safe ring
        llf[r] = (cc > 0)        ? l - 4   : l;
        ldn[r] = (cr < ER3 - 1)  ? l + EC3 : l;
        lrt[r] = (cc < NCH3 - 1) ? l + 4   : l;
        gj0a[r] = gj0;
        bdx[r] = (gi > 0);
        bgx[r] = (gi < HH - 1);
        wout[r] = wr[r] && (cr >= 3) && (cr <= 34) && (cc >= 1) && (cc <= 16);
        gw[r] = gi * WW + gj0;                 // in-image whenever wout

        // stage A: load p chunk + x chunk (regs), stage p into sA
        H2x4 v; v.f4 = *(const float4*)(pi + gofs);
        H2x2 xs; xs.f2 = *(const float2*)(xh + gofs);
        if (wr[r]) *(float4*)&sA[l] = v.f4;
        pc[r][0] = v.h2[0]; pc[r][1] = v.h2[1];
        pc[r][2] = v.h2[2]; pc[r][3] = v.h2[3];
        xf[r][0] = __low2float(xs.h2[0]); xf[r][1] = __high2float(xs.h2[0]);
        xf[r][2] = __low2float(xs.h2[1]); xf[r][3] = __high2float(xs.h2[1]);
    }
    __syncthreads();

    // u-stage: u = xh - C*div(p);  p from plane P (up/left) + own regs
    auto ustage = [&](const __half2* P) {
#pragma unroll
        for (int r = 0; r < 3; ++r) {
            H2x4 up; up.f4 = *(const float4*)(P + lup[r]);
            H2x4 lf; lf.f4 = *(const float4*)(P + llf[r]);
            float4 w; float* wp = &w.x;
#pragma unroll
            for (int e = 0; e < 4; ++e) {
                float dx = bdx[r]
                    ? (__low2float(up.h2[e]) - __low2float(pc[r][e])) : 0.f;
                __half2 le = (e == 0) ? lf.h2[3] : pc[r][e - 1];
                float dy = (gj0a[r] + e > 0)
                    ? (__high2float(le) - __high2float(pc[r][e])) : 0.f;
                float u = xf[r][e] - C_LAM * (dx + dy);
                uv[r][e] = u;
                wp[e] = u;
            }
            if (wr[r]) *(float4*)&sU[lb[r]] = w;
        }
    };

    // p-stage: p = clip(p + tau*grad(u)); u from sU (down/right) + own regs
    auto pstage = [&](__half2* Q, bool toLds, bool dow) {
#pragma unroll
        for (int r = 0; r < 3; ++r) {
            float4 dn = *(const float4*)&sU[ldn[r]];
            float4 rt = *(const float4*)&sU[lrt[r]];
            const float* dnp = &dn.x;
            H2x4 w;
#pragma unroll
            for (int e = 0; e < 4; ++e) {
                float gx = bgx[r] ? (dnp[e] - uv[r][e]) : 0.f;
                float rv = (e == 3) ? rt.x : uv[r][e + 1];
                float gy = (gj0a[r] + e < WW - 1) ? (rv - uv[r][e]) : 0.f;
                __half2 g = __floats2half2_rn(gx, gy);
                __half2 pn = clamp1h2(__hfma2(g, tau2, pc[r][e]));
                pc[r][e] = pn;
                w.h2[e] = pn;
            }
            if (toLds && wr[r]) *(float4*)&Q[lb[r]] = w.f4;
            if (dow && wout[r]) *(float4*)(po + gw[r]) = w.f4;
        }
    };

    ustage(sA); __syncthreads(); pstage(sB, true,  false); __syncthreads();
    ustage(sB); __syncthreads(); pstage(sA, true,  false); __syncthreads();
    ustage(sA); __syncthreads(); pstage(sB, false, true);
}

// -------- final: one more p-update (p49 -> p50) fused with the output --------
__global__ __launch_bounds__(256) void tv_last(const __half* __restrict__ xh,
                                               const float* __restrict__ x,
                                               const __half2* __restrict__ pi,
                                               float* __restrict__ out)
{
    __shared__ __half2 sp0[LSZ];
    __shared__ __half2 sp1[LSZ];
    __shared__ float   su [LSZ];

    const int tid  = threadIdx.x;
    const int lane = tid & 63;
    const int r0 = blockIdx.y * TH2;
    const int c0 = blockIdx.x * TW2;
    const __half2 tau2 = __float2half2_rn(TAU_F);

    int lb[3], lup[3], llf[3], ldn[3], lrt[3], gj0a[3], gofs[3];
    bool wr[3];
#pragma unroll
    for (int r = 0; r < 3; ++r) {
        int slot = tid + 256 * r;
        wr[r] = (slot < NSL);
        if (slot >= NSL) slot = NSL - 1;
        int cr = slot / NCH;
        int cc = slot - cr * NCH;
        int gi  = r0 - 2 + cr;
        int gj0 = c0 - 4 + cc * 4;
        int gic = min(max(gi, 0), HH - 1);
        int gjc = min(max(gj0, 0), WW - 4);
        gofs[r] = gic * WW + gjc;
        int l   = cr * ECC + cc * 4;
        lb[r]  = l;
        lup[r] = (cr > 0) ? l - ECC : l;
        llf[r] = (l > 0) ? l - 1 : 0;
        ldn[r] = (cr < ERR - 1) ? l + ECC : l;
        lrt[r] = min(l + 4, LSZ - 1);
        gj0a[r] = gj0;
    }

    __half2 c2[3][4];
    H2x2    xc[3];
#pragma unroll
    for (int r = 0; r < 3; ++r) {
        H2x4 v; v.f4 = *(const float4*)(pi + gofs[r]);
        xc[r].f2    = *(const float2*)(xh + gofs[r]);
        if (wr[r]) *(float4*)&sp0[lb[r]] = v.f4;
        c2[r][0] = v.h2[0]; c2[r][1] = v.h2[1];
        c2[r][2] = v.h2[2]; c2[r][3] = v.h2[3];
    }
    __syncthreads();

    float u1v[3][4];
#pragma unroll
    for (int r = 0; r < 3; ++r) {
        H2x4 up; up.f4 = *(float4*)&sp0[lup[r]];
        __half2 lf = shfl_up_h2(c2[r][3]);
        if (lane == 0) lf = sp0[llf[r]];
        float xs[4] = {__low2float(xc[r].h2[0]), __high2float(xc[r].h2[0]),
                       __low2float(xc[r].h2[1]), __high2float(xc[r].h2[1])};
        float4 w;
        float* wp = &w.x;
#pragma unroll
        for (int e = 0; e < 4; ++e) {
            __half2 cc = c2[r][e];
            __half2 le = (e == 0) ? lf : c2[r][e - 1];
            float dx = __low2float(up.h2[e]) - __low2float(cc);
            float dy = __high2float(le) - __high2float(cc);
            dy = (gj0a[r] + e > 0) ? dy : 0.f;
            float u = xs[e] - C_LAM * (dx + dy);
            u1v[r][e] = u;
            wp[e] = u;
        }
        if (wr[r]) *(float4*)&su[lb[r]] = w;
    }
    __syncthreads();

#pragma unroll
    for (int r = 0; r < 3; ++r) {
        float4 dn4 = *(float4*)&su[ldn[r]];
        float urr = __shfl_down(u1v[r][0], 1, 64);
        if (lane == 63) urr = su[lrt[r]];
        float dn[4] = {dn4.x, dn4.y, dn4.z, dn4.w};
        H2x4 w;
#pragma unroll
        for (int e = 0; e < 4; ++e) {
            float uc = u1v[r][e];
            float gx = dn[e] - uc;
            float rt = (e == 3) ? urr : u1v[r][e + 1];
            float gy = (gj0a[r] + e < WW - 1) ? (rt - uc) : 0.f;
            __half2 g = __float22half2_rn(make_float2(gx, gy));
            w.h2[e] = clamp1h2(__hfma2(g, tau2, c2[r][e]));
        }
        if (wr[r]) *(float4*)&sp1[lb[r]] = w.f4;
    }
    __syncthreads();

    // out = x - c*div(p50) on interior
#pragma unroll
    for (int r = 0; r < 2; ++r) {
        int slot = tid + 256 * r;
        int ir = slot >> 4, icc = slot & 15;
        int er = ir + 2, ec = icc * 4 + 4;
        int l  = er * ECC + ec;
        int gi = r0 + ir, gj = c0 + icc * 4;

        H2x4 pc_; pc_.f4 = *(float4*)&sp1[l];
        H2x4 pu_; pu_.f4 = *(float4*)&sp1[l - ECC];
        __half2 plf = shfl_up_h2(pc_.h2[3]);
        if ((tid & 15) == 0) plf = sp1[l - 1];

        float4 xr4 = *(const float4*)(x + (size_t)gi * WW + gj);
        float xv[4] = {xr4.x, xr4.y, xr4.z, xr4.w};
        float o[4];
#pragma unroll
        for (int e = 0; e < 4; ++e) {
            __half2 cc = pc_.h2[e];
            __half2 le = (e == 0) ? plf : pc_.h2[e - 1];
            float dx = __low2float(pu_.h2[e]) - __low2float(cc);
            dx = (gi > 0) ? dx : 0.f;
            float dy = __high2float(le) - __high2float(cc);
            dy = (gj + e > 0) ? dy : 0.f;
            o[e] = xv[e] - C_LAM * (dx + dy);
        }
        *(float4*)(out + (size_t)gi * WW + gj) = make_float4(o[0], o[1], o[2], o[3]);
    }
}

extern "C" void kernel_launch(void* const* d_in, const int* in_sizes, int n_in,
                              void* d_out, int out_size, void* d_ws, size_t ws_size,
                              hipStream_t stream)
{
    const float* x = (const float*)d_in[0];
    float* out = (float*)d_out;
    const size_t N = (size_t)HH * (size_t)WW;

    // ws layout: pA (64 MiB) | pB (64 MiB) | x_h (32 MiB)
    __half2* pA = (__half2*)d_ws;
    __half2* pB = pA + N;
    __half*  xh = (__half*)(pB + N);

    dim3 b1(BX, BY), g1(WW / TILE_W, HH / BY);
    dim3 b3(256),    g3(WW / TW2, HH / TH2);

    tv_first<<<g1, b1, 0, stream>>>(x, pA, xh);              // iter 1
    __half2 *pin = pA, *pout = pB;
    for (int p = 0; p < 16; ++p) {                           // iters 2..49 (16x3)
        tv_iter3<<<g3, b3, 0, stream>>>(xh, pin, pout);
        __half2* t = pin; pin = pout; pout = t;
    }
    tv_last<<<g3, b3, 0, stream>>>(xh, x, pin, out);         // iter 50 + output
}

// Round 9
// 871.739 us; speedup vs baseline: 1.3388x; 1.2519x over previous
//
#include <hip/hip_runtime.h>
#include <hip/hip_fp16.h>

#define HH 4096
#define WW 4096

constexpr float C_LAM = 0.1f;   // ALPHA * LAMDA
constexpr float TAU_F = 0.25f;

// ---- first-iteration kernel geometry ----
#define BX 64
#define BY 8
#define VEC 4
#define TILE_W (BX * VEC)       // 256 cols per block

// ---- tv_last (2-ring) geometry ----
#define TW2 64
#define TH2 32
#define ERR 36
#define ECC 72
#define NCH (ECC / 4)
#define NSL (ERR * NCH)         // 648
#define LSZ (ERR * ECC)         // 2592

// ---- tv_iter3 (3-ring) geometry ----
#define ER3 38                  // rows [r0-3, r0+34]
#define EC3 72                  // cols [c0-4, c0+67]
#define NCH3 (EC3 / 4)          // 18
#define NSL3 (ER3 * NCH3)       // 684 chunk-slots
#define LSZ3 (ER3 * EC3)        // 2736 pixels per plane

typedef float __attribute__((ext_vector_type(4))) f32x4_t;
typedef float __attribute__((ext_vector_type(2))) f32x2_t;

union H2x4 { float4 f4; f32x4_t v4; __half2 h2[4]; };
union H2x2 { float2 f2; f32x2_t v2; __half2 h2[2]; };
union H2U  { __half2 h; unsigned int u; };

__device__ __forceinline__ float clip1(float v) {
    return fminf(1.0f, fmaxf(-1.0f, v));
}

// packed clamp to [-1,1] (no __hmax2/__hmin2 in ROCm 7.2 headers)
__device__ __forceinline__ __half2 clamp1h2(__half2 v) {
    H2U a; a.h = v;
    unsigned int lo = 0xBC00BC00u;   // (-1, -1) fp16
    unsigned int hi = 0x3C003C00u;   // (+1, +1) fp16
    unsigned int t, r;
    asm("v_pk_max_f16 %0, %1, %2" : "=v"(t) : "v"(a.u), "v"(lo));
    asm("v_pk_min_f16 %0, %1, %2" : "=v"(r) : "v"(t),   "v"(hi));
    H2U b; b.u = r;
    return b.h;
}

__device__ __forceinline__ __half2 shfl_up_h2(__half2 v) {
    H2U a; a.h = v;
    int s = __shfl_up((int)a.u, 1, 64);
    H2U b; b.u = (unsigned)s;
    return b.h;
}

// iteration 0 (p=0 -> u=x):  p = clip(tau * grad(x)); also emits x_h = fp16(x)
__global__ __launch_bounds__(512) void tv_first(const float* __restrict__ x,
                                                __half2* __restrict__ po,
                                                __half* __restrict__ xh)
{
    const int tx = threadIdx.x, ty = threadIdx.y;
    const int i = blockIdx.y * BY + ty;
    const int j = blockIdx.x * TILE_W + tx * VEC;
    const size_t idx = (size_t)i * WW + j;

    float4 xc4 = *(const float4*)(x + idx);
    float4 xd4 = make_float4(0.f, 0.f, 0.f, 0.f);
    if (i < HH - 1) xd4 = *(const float4*)(x + idx + WW);

    float c[4] = {xc4.x, xc4.y, xc4.z, xc4.w};
    float d[4] = {xd4.x, xd4.y, xd4.z, xd4.w};

    float xr = __shfl_down(c[0], 1, 64);
    if (tx == BX - 1 && j + VEC < WW) xr = x[idx + VEC];

    H2x4 o;
#pragma unroll
    for (int e = 0; e < 4; ++e) {
        float gx = (i < HH - 1) ? (d[e] - c[e]) : 0.f;
        float rn = (e < 3) ? c[e + 1] : xr;
        float gy = (j + e < WW - 1) ? (rn - c[e]) : 0.f;
        o.h2[e] = __floats2half2_rn(clip1(TAU_F * gx), clip1(TAU_F * gy));
    }
    *(float4*)(po + idx) = o.f4;

    H2x2 xs;
    xs.h2[0] = __floats2half2_rn(c[0], c[1]);
    xs.h2[1] = __floats2half2_rn(c[2], c[3]);
    *(float2*)(xh + idx) = xs.f2;
}

// -------- three fused Chambolle steps per pass --------
// p planes (half2 per pixel) ping-pong in LDS; u plane fp16. Own chunk in
// registers across stages; neighbor chunks read as FULL contiguous vectors
// (asm keepalive prevents the compiler narrowing them into strided scalar
// reads -> 8-way bank conflicts, the R8 regression).
template<bool EDGE>
__device__ __forceinline__ void iter3_body(const __half* __restrict__ xh,
                                           const __half2* __restrict__ pi,
                                           __half2* __restrict__ po,
                                           __half2* sA, __half2* sB, __half* sU)
{
    const int tid = threadIdx.x;
    const int r0 = blockIdx.y * TH2;
    const int c0 = blockIdx.x * TW2;
    const __half2 tau2 = __float2half2_rn(TAU_F);

    int lb[3], lup[3], llf[3], ldn[3], lrt[3], gj0a[3], gw[3];
    bool wr[3], wout[3], bdx[3], bgx[3];
    __half2 pc[3][4];
    float xf[3][4], uv[3][4];

#pragma unroll
    for (int r = 0; r < 3; ++r) {
        int slot = tid + 256 * r;
        wr[r] = (slot < NSL3);
        if (!wr[r]) slot = NSL3 - 1;           // dup slot: same data, writes masked
        int cr = slot / NCH3;
        int cc = slot - cr * NCH3;
        int gi  = r0 - 3 + cr;
        int gj0 = c0 - 4 + cc * 4;
        int gic = min(max(gi, 0), HH - 1);
        int gjc = min(max(gj0, 0), WW - 4);
        int gofs = gic * WW + gjc;
        int l = cr * EC3 + cc * 4;
        lb[r]  = l;
        lup[r] = (cr > 0)        ? l - EC3 : l;   // clamp: garbage-safe ring
        llf[r] = (cc > 0)        ? l - 4   : l;
        ldn[r] = (cr < ER3 - 1)  ? l + EC3 : l;
        lrt[r] = (cc < NCH3 - 1) ? l + 4   : l;
        gj0a[r] = gj0;
        bdx[r] = (gi > 0);
        bgx[r] = (gi < HH - 1);
        wout[r] = wr[r] && (cr >= 3) && (cr <= 34) && (cc >= 1) && (cc <= 16);
        gw[r] = gi * WW + gj0;

        // stage A: load p chunk + x chunk; stage p into sA
        H2x4 v; v.v4 = *(const f32x4_t*)(pi + gofs);
        H2x2 xs; xs.v2 = *(const f32x2_t*)(xh + gofs);
        if (wr[r]) *(f32x4_t*)&sA[l] = v.v4;
        pc[r][0] = v.h2[0]; pc[r][1] = v.h2[1];
        pc[r][2] = v.h2[2]; pc[r][3] = v.h2[3];
        xf[r][0] = __low2float(xs.h2[0]); xf[r][1] = __high2float(xs.h2[0]);
        xf[r][2] = __low2float(xs.h2[1]); xf[r][3] = __high2float(xs.h2[1]);
    }
    __syncthreads();

    // u-stage: u = xh - C*div(p); up/left neighbor chunks from plane P
    auto ustage = [&](const __half2* P) {
#pragma unroll
        for (int r = 0; r < 3; ++r) {
            H2x4 up; up.v4 = *(const f32x4_t*)(P + lup[r]);
            asm volatile("" : "+v"(up.v4));        // keep full b128 load
            H2x4 lf; lf.v4 = *(const f32x4_t*)(P + llf[r]);
            asm volatile("" : "+v"(lf.v4));        // keep full b128 load
            H2x2 w;
            float u0, u1, u2, u3;
#pragma unroll
            for (int e = 0; e < 4; ++e) {
                __half2 t1 = __hsub2(up.h2[e], pc[r][e]);          // .lo = dx
                __half2 le = (e == 0) ? lf.h2[3] : pc[r][e - 1];
                __half2 t2 = __hsub2(le, pc[r][e]);                // .hi = dy
                float dx = __low2float(t1);
                float dy = __high2float(t2);
                if (EDGE) {
                    dx = bdx[r] ? dx : 0.f;
                    dy = (gj0a[r] + e > 0) ? dy : 0.f;
                }
                float u = fmaf(-C_LAM, dx + dy, xf[r][e]);
                uv[r][e] = u;
                if (e == 0) u0 = u; else if (e == 1) u1 = u;
                else if (e == 2) u2 = u; else u3 = u;
            }
            w.h2[0] = __floats2half2_rn(u0, u1);
            w.h2[1] = __floats2half2_rn(u2, u3);
            if (wr[r]) *(f32x2_t*)&sU[lb[r]] = w.v2;
        }
    };

    // p-stage: p = clip(p + tau*grad(u)); down/right u from sU
    auto pstage = [&](__half2* Q, bool toLds, bool dow) {
#pragma unroll
        for (int r = 0; r < 3; ++r) {
            H2x2 dn; dn.v2 = *(const f32x2_t*)&sU[ldn[r]];
            H2x2 rt; rt.v2 = *(const f32x2_t*)&sU[lrt[r]];
            asm volatile("" : "+v"(rt.v2));        // keep full b64 load
            float dnf[4] = {__low2float(dn.h2[0]), __high2float(dn.h2[0]),
                            __low2float(dn.h2[1]), __high2float(dn.h2[1])};
            float rtf = __low2float(rt.h2[0]);
            H2x4 w;
#pragma unroll
            for (int e = 0; e < 4; ++e) {
                float gx = dnf[e] - uv[r][e];
                float rv = (e == 3) ? rtf : uv[r][e + 1];
                float gy = rv - uv[r][e];
                if (EDGE) {
                    gx = bgx[r] ? gx : 0.f;
                    gy = (gj0a[r] + e < WW - 1) ? gy : 0.f;
                }
                __half2 g = __floats2half2_rn(gx, gy);
                __half2 pn = clamp1h2(__hfma2(g, tau2, pc[r][e]));
                pc[r][e] = pn;
                w.h2[e] = pn;
            }
            if (toLds && wr[r]) *(f32x4_t*)&Q[lb[r]] = w.v4;
            if (dow && wout[r]) *(f32x4_t*)(po + gw[r]) = w.v4;
        }
    };

    ustage(sA); __syncthreads(); pstage(sB, true,  false); __syncthreads();
    ustage(sB); __syncthreads(); pstage(sA, true,  false); __syncthreads();
    ustage(sA); __syncthreads(); pstage(sB, false, true);
}

__global__ __launch_bounds__(256) void tv_iter3(const __half* __restrict__ xh,
                                                const __half2* __restrict__ pi,
                                                __half2* __restrict__ po)
{
    __shared__ __align__(16) __half2 sA[LSZ3];
    __shared__ __align__(16) __half2 sB[LSZ3];
    __shared__ __align__(16) __half  sU[LSZ3];

    const bool edge = (blockIdx.x == 0) || (blockIdx.x == gridDim.x - 1) ||
                      (blockIdx.y == 0) || (blockIdx.y == gridDim.y - 1);
    if (!edge) iter3_body<false>(xh, pi, po, sA, sB, sU);
    else       iter3_body<true >(xh, pi, po, sA, sB, sU);
}

// -------- final: one more p-update (p49 -> p50) fused with the output --------
__global__ __launch_bounds__(256) void tv_last(const __half* __restrict__ xh,
                                               const float* __restrict__ x,
                                               const __half2* __restrict__ pi,
                                               float* __restrict__ out)
{
    __shared__ __half2 sp0[LSZ];
    __shared__ __half2 sp1[LSZ];
    __shared__ float   su [LSZ];

    const int tid  = threadIdx.x;
    const int lane = tid & 63;
    const int r0 = blockIdx.y * TH2;
    const int c0 = blockIdx.x * TW2;
    const __half2 tau2 = __float2half2_rn(TAU_F);

    int lb[3], lup[3], llf[3], ldn[3], lrt[3], gj0a[3], gofs[3];
    bool wr[3];
#pragma unroll
    for (int r = 0; r < 3; ++r) {
        int slot = tid + 256 * r;
        wr[r] = (slot < NSL);
        if (slot >= NSL) slot = NSL - 1;
        int cr = slot / NCH;
        int cc = slot - cr * NCH;
        int gi  = r0 - 2 + cr;
        int gj0 = c0 - 4 + cc * 4;
        int gic = min(max(gi, 0), HH - 1);
        int gjc = min(max(gj0, 0), WW - 4);
        gofs[r] = gic * WW + gjc;
        int l   = cr * ECC + cc * 4;
        lb[r]  = l;
        lup[r] = (cr > 0) ? l - ECC : l;
        llf[r] = (l > 0) ? l - 1 : 0;
        ldn[r] = (cr < ERR - 1) ? l + ECC : l;
        lrt[r] = min(l + 4, LSZ - 1);
        gj0a[r] = gj0;
    }

    __half2 c2[3][4];
    H2x2    xc[3];
#pragma unroll
    for (int r = 0; r < 3; ++r) {
        H2x4 v; v.f4 = *(const float4*)(pi + gofs[r]);
        xc[r].f2    = *(const float2*)(xh + gofs[r]);
        if (wr[r]) *(float4*)&sp0[lb[r]] = v.f4;
        c2[r][0] = v.h2[0]; c2[r][1] = v.h2[1];
        c2[r][2] = v.h2[2]; c2[r][3] = v.h2[3];
    }
    __syncthreads();

    float u1v[3][4];
#pragma unroll
    for (int r = 0; r < 3; ++r) {
        H2x4 up; up.f4 = *(float4*)&sp0[lup[r]];
        __half2 lf = shfl_up_h2(c2[r][3]);
        if (lane == 0) lf = sp0[llf[r]];
        float xs[4] = {__low2float(xc[r].h2[0]), __high2float(xc[r].h2[0]),
                       __low2float(xc[r].h2[1]), __high2float(xc[r].h2[1])};
        float4 w;
        float* wp = &w.x;
#pragma unroll
        for (int e = 0; e < 4; ++e) {
            __half2 cc = c2[r][e];
            __half2 le = (e == 0) ? lf : c2[r][e - 1];
            float dx = __low2float(up.h2[e]) - __low2float(cc);
            float dy = __high2float(le) - __high2float(cc);
            dy = (gj0a[r] + e > 0) ? dy : 0.f;
            float u = xs[e] - C_LAM * (dx + dy);
            u1v[r][e] = u;
            wp[e] = u;
        }
        if (wr[r]) *(float4*)&su[lb[r]] = w;
    }
    __syncthreads();

#pragma unroll
    for (int r = 0; r < 3; ++r) {
        float4 dn4 = *(float4*)&su[ldn[r]];
        float urr = __shfl_down(u1v[r][0], 1, 64);
        if (lane == 63) urr = su[lrt[r]];
        float dn[4] = {dn4.x, dn4.y, dn4.z, dn4.w};
        H2x4 w;
#pragma unroll
        for (int e = 0; e < 4; ++e) {
            float uc = u1v[r][e];
            float gx = dn[e] - uc;
            float rt = (e == 3) ? urr : u1v[r][e + 1];
            float gy = (gj0a[r] + e < WW - 1) ? (rt - uc) : 0.f;
            __half2 g = __float22half2_rn(make_float2(gx, gy));
            w.h2[e] = clamp1h2(__hfma2(g, tau2, c2[r][e]));
        }
        if (wr[r]) *(float4*)&sp1[lb[r]] = w.f4;
    }
    __syncthreads();

    // out = x - c*div(p50) on interior
#pragma unroll
    for (int r = 0; r < 2; ++r) {
        int slot = tid + 256 * r;
        int ir = slot >> 4, icc = slot & 15;
        int er = ir + 2, ec = icc * 4 + 4;
        int l  = er * ECC + ec;
        int gi = r0 + ir, gj = c0 + icc * 4;

        H2x4 pc_; pc_.f4 = *(float4*)&sp1[l];
        H2x4 pu_; pu_.f4 = *(float4*)&sp1[l - ECC];
        __half2 plf = shfl_up_h2(pc_.h2[3]);
        if ((tid & 15) == 0) plf = sp1[l - 1];

        float4 xr4 = *(const float4*)(x + (size_t)gi * WW + gj);
        float xv[4] = {xr4.x, xr4.y, xr4.z, xr4.w};
        float o[4];
#pragma unroll
        for (int e = 0; e < 4; ++e) {
            __half2 cc = pc_.h2[e];
            __half2 le = (e == 0) ? plf : pc_.h2[e - 1];
            float dx = __low2float(pu_.h2[e]) - __low2float(cc);
            dx = (gi > 0) ? dx : 0.f;
            float dy = __high2float(le) - __high2float(cc);
            dy = (gj + e > 0) ? dy : 0.f;
            o[e] = xv[e] - C_LAM * (dx + dy);
        }
        *(float4*)(out + (size_t)gi * WW + gj) = make_float4(o[0], o[1], o[2], o[3]);
    }
}

extern "C" void kernel_launch(void* const* d_in, const int* in_sizes, int n_in,
                              void* d_out, int out_size, void* d_ws, size_t ws_size,
                              hipStream_t stream)
{
    const float* x = (const float*)d_in[0];
    float* out = (float*)d_out;
    const size_t N = (size_t)HH * (size_t)WW;

    // ws layout: pA (64 MiB) | pB (64 MiB) | x_h (32 MiB)
    __half2* pA = (__half2*)d_ws;
    __half2* pB = pA + N;
    __half*  xh = (__half*)(pB + N);

    dim3 b1(BX, BY), g1(WW / TILE_W, HH / BY);
    dim3 b3(256),    g3(WW / TW2, HH / TH2);

    tv_first<<<g1, b1, 0, stream>>>(x, pA, xh);              // iter 1
    __half2 *pin = pA, *pout = pB;
    for (int p = 0; p < 16; ++p) {                           // iters 2..49 (16x3)
        tv_iter3<<<g3, b3, 0, stream>>>(xh, pin, pout);
        __half2* t = pin; pin = pout; pout = t;
    }
    tv_last<<<g3, b3, 0, stream>>>(xh, x, pin, out);         // iter 50 + output
}

// Round 10
// 807.342 us; speedup vs baseline: 1.4455x; 1.0798x over previous
//
#include <hip/hip_runtime.h>
#include <hip/hip_fp16.h>

#define HH 4096
#define WW 4096

constexpr float C_LAM = 0.1f;   // ALPHA * LAMDA
constexpr float TAU_F = 0.25f;

// ---- first-iteration kernel geometry ----
#define BX 64
#define BY 8
#define VEC 4
#define TILE_W (BX * VEC)       // 256 cols per block

// ---- tv_last (2-ring) geometry ----
#define TW2 64
#define TH2 32
#define ERR 36
#define ECC 72
#define NCH (ECC / 4)
#define NSL (ERR * NCH)         // 648
#define LSZ (ERR * ECC)         // 2592

// ---- tv_iter3 (3-ring) geometry ----
#define ER3 38                  // rows [r0-3, r0+34]
#define EC3 72                  // cols [c0-4, c0+67]
#define NCH3 (EC3 / 4)          // 18
#define NSL3 (ER3 * NCH3)       // 684 chunk-slots
#define LSZ3 (ER3 * EC3)        // 2736 pixels per plane

typedef float __attribute__((ext_vector_type(4))) f32x4_t;
typedef float __attribute__((ext_vector_type(2))) f32x2_t;

union H2x4 { float4 f4; f32x4_t v4; __half2 h2[4]; unsigned u32[4]; };
union H2x2 { float2 f2; f32x2_t v2; __half2 h2[2]; unsigned u32[2]; };
union H2U  { __half2 h; unsigned int u; };

__device__ __forceinline__ float clip1(float v) {
    return fminf(1.0f, fmaxf(-1.0f, v));
}

// packed clamp to [-1,1] (no __hmax2/__hmin2 in ROCm 7.2 headers)
__device__ __forceinline__ __half2 clamp1h2(__half2 v) {
    H2U a; a.h = v;
    unsigned int lo = 0xBC00BC00u;   // (-1, -1) fp16
    unsigned int hi = 0x3C003C00u;   // (+1, +1) fp16
    unsigned int t, r;
    asm("v_pk_max_f16 %0, %1, %2" : "=v"(t) : "v"(a.u), "v"(lo));
    asm("v_pk_min_f16 %0, %1, %2" : "=v"(r) : "v"(t),   "v"(hi));
    H2U b; b.u = r;
    return b.h;
}

__device__ __forceinline__ __half2 shfl_up_h2(__half2 v) {
    H2U a; a.h = v;
    int s = __shfl_up((int)a.u, 1, 64);
    H2U b; b.u = (unsigned)s;
    return b.h;
}

// (hi:lo) >> 16, as __half2: result = (lo.hi, hi.lo)
__device__ __forceinline__ __half2 align16(__half2 hi, __half2 lo) {
    H2U a, b, d;
    a.h = hi; b.h = lo;
    asm("v_alignbit_b32 %0, %1, %2, 16" : "=v"(d.u) : "v"(a.u), "v"(b.u));
    return d.h;
}

// iteration 0 (p=0 -> u=x):  p = clip(tau * grad(x)); also emits x_h = fp16(x)
__global__ __launch_bounds__(512) void tv_first(const float* __restrict__ x,
                                                __half2* __restrict__ po,
                                                __half* __restrict__ xh)
{
    const int tx = threadIdx.x, ty = threadIdx.y;
    const int i = blockIdx.y * BY + ty;
    const int j = blockIdx.x * TILE_W + tx * VEC;
    const size_t idx = (size_t)i * WW + j;

    float4 xc4 = *(const float4*)(x + idx);
    float4 xd4 = make_float4(0.f, 0.f, 0.f, 0.f);
    if (i < HH - 1) xd4 = *(const float4*)(x + idx + WW);

    float c[4] = {xc4.x, xc4.y, xc4.z, xc4.w};
    float d[4] = {xd4.x, xd4.y, xd4.z, xd4.w};

    float xr = __shfl_down(c[0], 1, 64);
    if (tx == BX - 1 && j + VEC < WW) xr = x[idx + VEC];

    H2x4 o;
#pragma unroll
    for (int e = 0; e < 4; ++e) {
        float gx = (i < HH - 1) ? (d[e] - c[e]) : 0.f;
        float rn = (e < 3) ? c[e + 1] : xr;
        float gy = (j + e < WW - 1) ? (rn - c[e]) : 0.f;
        o.h2[e] = __floats2half2_rn(clip1(TAU_F * gx), clip1(TAU_F * gy));
    }
    *(float4*)(po + idx) = o.f4;

    H2x2 xs;
    xs.h2[0] = __floats2half2_rn(c[0], c[1]);
    xs.h2[1] = __floats2half2_rn(c[2], c[3]);
    *(float2*)(xh + idx) = xs.f2;
}

// -------- three fused Chambolle steps, fully packed fp16 SoA --------
// Global p stays interleaved __half2; deinterleaved once via v_perm into
// SoA LDS planes (px, py ping-pong + u). All stencil math is packed-fp16:
// hsub2/hadd2/hfma2 + alignbit shifts + pk_max/min clamps. Neighbor chunks
// read as full b64 vectors (keepalive where partially used, per R9).
template<bool EDGE>
__device__ __forceinline__ void iter3_body(const __half* __restrict__ xh,
                                           const __half2* __restrict__ pi,
                                           __half2* __restrict__ po,
                                           __half* sPxA, __half* sPxB,
                                           __half* sPyA, __half* sPyB,
                                           __half* sU)
{
    const int tid = threadIdx.x;
    const int r0 = blockIdx.y * TH2;
    const int c0 = blockIdx.x * TW2;
    const __half2 tau2 = __float2half2_rn(TAU_F);
    const __half2 nC2  = __float2half2_rn(-C_LAM);
    const unsigned SEL0 = 0x05040100u, SEL1 = 0x07060302u;

    int lb[3], lup[3], llf[3], ldn[3], lrt[3], gw[3];
    unsigned mdy[3], mgy[3];
    bool wr[3], wout[3], bdx[3], bgx[3];
    __half2 X[3][2], Y[3][2], XH[3][2], U[3][2];

    // ---- setup + stage A: load interleaved p + xh; deinterleave; stage ----
#pragma unroll
    for (int r = 0; r < 3; ++r) {
        int slot = tid + 256 * r;
        wr[r] = (slot < NSL3);
        if (!wr[r]) slot = NSL3 - 1;          // dup slot: writes masked
        int cr = slot / NCH3;
        int cc = slot - cr * NCH3;
        int gi  = r0 - 3 + cr;
        int gj0 = c0 - 4 + cc * 4;
        int gic = min(max(gi, 0), HH - 1);
        int gjc = min(max(gj0, 0), WW - 4);
        int gofs = gic * WW + gjc;
        int l = cr * EC3 + cc * 4;
        lb[r]  = l;
        lup[r] = (cr > 0)        ? l - EC3 : l;   // clamp: garbage-safe ring
        llf[r] = (cc > 0)        ? l - 4   : l;
        ldn[r] = (cr < ER3 - 1)  ? l + EC3 : l;
        lrt[r] = (cc < NCH3 - 1) ? l + 4   : l;
        bdx[r] = (gi > 0);
        bgx[r] = (gi < HH - 1);
        mdy[r] = (gj0 == 0)      ? 0xFFFF0000u : 0xFFFFFFFFu;  // zero dy at j=0
        mgy[r] = (gj0 + 4 == WW) ? 0x0000FFFFu : 0xFFFFFFFFu;  // zero gy at j=WW-1
        wout[r] = wr[r] && (cr >= 3) && (cr <= 34) && (cc >= 1) && (cc <= 16);
        gw[r] = gi * WW + gj0;

        H2x4 v;  v.v4  = *(const f32x4_t*)(pi + gofs);
        H2x2 xs; xs.v2 = *(const f32x2_t*)(xh + gofs);
        H2U xa, xb, ya, yb;
        asm("v_perm_b32 %0, %1, %2, %3" : "=v"(xa.u) : "v"(v.u32[1]), "v"(v.u32[0]), "v"(SEL0));
        asm("v_perm_b32 %0, %1, %2, %3" : "=v"(ya.u) : "v"(v.u32[1]), "v"(v.u32[0]), "v"(SEL1));
        asm("v_perm_b32 %0, %1, %2, %3" : "=v"(xb.u) : "v"(v.u32[3]), "v"(v.u32[2]), "v"(SEL0));
        asm("v_perm_b32 %0, %1, %2, %3" : "=v"(yb.u) : "v"(v.u32[3]), "v"(v.u32[2]), "v"(SEL1));
        X[r][0] = xa.h; X[r][1] = xb.h;
        Y[r][0] = ya.h; Y[r][1] = yb.h;
        XH[r][0] = xs.h2[0]; XH[r][1] = xs.h2[1];
        if (wr[r]) {
            H2x2 wx; wx.h2[0] = X[r][0]; wx.h2[1] = X[r][1];
            *(f32x2_t*)(sPxA + l) = wx.v2;
            H2x2 wy; wy.h2[0] = Y[r][0]; wy.h2[1] = Y[r][1];
            *(f32x2_t*)(sPyA + l) = wy.v2;
        }
    }
    __syncthreads();

    // u = xh - C*div(p):  dx = up - own (SoA px), dy = left-shifted py - py
    auto ustage = [&](const __half* Px, const __half* Py) {
#pragma unroll
        for (int r = 0; r < 3; ++r) {
            H2x2 up; up.v2 = *(const f32x2_t*)(Px + lup[r]);
            H2x2 lf; lf.v2 = *(const f32x2_t*)(Py + llf[r]);
            asm volatile("" : "+v"(lf.v2));        // keep full b64 load
            __half2 zm0 = align16(Y[r][0], lf.h2[1]);  // (pyL3, py0)
            __half2 zm1 = align16(Y[r][1], Y[r][0]);   // (py1, py2)
            __half2 dx0 = __hsub2(up.h2[0], X[r][0]);
            __half2 dx1 = __hsub2(up.h2[1], X[r][1]);
            __half2 dy0 = __hsub2(zm0, Y[r][0]);
            __half2 dy1 = __hsub2(zm1, Y[r][1]);
            if (EDGE) {
                H2U z; z.u = 0u;
                if (!bdx[r]) { dx0 = z.h; dx1 = z.h; }
                H2U a; a.h = dy0; a.u &= mdy[r]; dy0 = a.h;
            }
            __half2 u0 = __hfma2(__hadd2(dx0, dy0), nC2, XH[r][0]);
            __half2 u1 = __hfma2(__hadd2(dx1, dy1), nC2, XH[r][1]);
            U[r][0] = u0; U[r][1] = u1;
            if (wr[r]) {
                H2x2 w; w.h2[0] = u0; w.h2[1] = u1;
                *(f32x2_t*)(sU + lb[r]) = w.v2;
            }
        }
    };

    // p = clip(p + tau*grad(u)):  gx = down - own, gy = right-shifted u - u
    auto pstage = [&](__half* QPx, __half* QPy, bool toLds, bool dow) {
#pragma unroll
        for (int r = 0; r < 3; ++r) {
            H2x2 dn; dn.v2 = *(const f32x2_t*)(sU + ldn[r]);
            H2x2 rt; rt.v2 = *(const f32x2_t*)(sU + lrt[r]);
            asm volatile("" : "+v"(rt.v2));        // keep full b64 load
            __half2 zp0 = align16(U[r][1], U[r][0]);   // (u1, u2)
            __half2 zp1 = align16(rt.h2[0], U[r][1]);  // (u3, r0)
            __half2 gx0 = __hsub2(dn.h2[0], U[r][0]);
            __half2 gx1 = __hsub2(dn.h2[1], U[r][1]);
            __half2 gy0 = __hsub2(zp0, U[r][0]);
            __half2 gy1 = __hsub2(zp1, U[r][1]);
            if (EDGE) {
                H2U z; z.u = 0u;
                if (!bgx[r]) { gx0 = z.h; gx1 = z.h; }
                H2U a; a.h = gy1; a.u &= mgy[r]; gy1 = a.h;
            }
            X[r][0] = clamp1h2(__hfma2(gx0, tau2, X[r][0]));
            X[r][1] = clamp1h2(__hfma2(gx1, tau2, X[r][1]));
            Y[r][0] = clamp1h2(__hfma2(gy0, tau2, Y[r][0]));
            Y[r][1] = clamp1h2(__hfma2(gy1, tau2, Y[r][1]));
            if (toLds && wr[r]) {
                H2x2 wx; wx.h2[0] = X[r][0]; wx.h2[1] = X[r][1];
                *(f32x2_t*)(QPx + lb[r]) = wx.v2;
                H2x2 wy; wy.h2[0] = Y[r][0]; wy.h2[1] = Y[r][1];
                *(f32x2_t*)(QPy + lb[r]) = wy.v2;
            }
            if (dow && wout[r]) {
                H2U xx0, xx1, yy0, yy1;
                xx0.h = X[r][0]; xx1.h = X[r][1];
                yy0.h = Y[r][0]; yy1.h = Y[r][1];
                H2x4 w;
                asm("v_perm_b32 %0, %1, %2, %3" : "=v"(w.u32[0]) : "v"(yy0.u), "v"(xx0.u), "v"(SEL0));
                asm("v_perm_b32 %0, %1, %2, %3" : "=v"(w.u32[1]) : "v"(yy0.u), "v"(xx0.u), "v"(SEL1));
                asm("v_perm_b32 %0, %1, %2, %3" : "=v"(w.u32[2]) : "v"(yy1.u), "v"(xx1.u), "v"(SEL0));
                asm("v_perm_b32 %0, %1, %2, %3" : "=v"(w.u32[3]) : "v"(yy1.u), "v"(xx1.u), "v"(SEL1));
                *(f32x4_t*)(po + gw[r]) = w.v4;
            }
        }
    };

    ustage(sPxA, sPyA); __syncthreads();
    pstage(sPxB, sPyB, true, false); __syncthreads();
    ustage(sPxB, sPyB); __syncthreads();
    pstage(sPxA, sPyA, true, false); __syncthreads();
    ustage(sPxA, sPyA); __syncthreads();
    pstage(nullptr, nullptr, false, true);
}

__global__ __launch_bounds__(256) void tv_iter3(const __half* __restrict__ xh,
                                                const __half2* __restrict__ pi,
                                                __half2* __restrict__ po)
{
    __shared__ __align__(16) __half sPxA[LSZ3];
    __shared__ __align__(16) __half sPxB[LSZ3];
    __shared__ __align__(16) __half sPyA[LSZ3];
    __shared__ __align__(16) __half sPyB[LSZ3];
    __shared__ __align__(16) __half sU[LSZ3];

    const bool edge = (blockIdx.x == 0) || (blockIdx.x == gridDim.x - 1) ||
                      (blockIdx.y == 0) || (blockIdx.y == gridDim.y - 1);
    if (!edge) iter3_body<false>(xh, pi, po, sPxA, sPxB, sPyA, sPyB, sU);
    else       iter3_body<true >(xh, pi, po, sPxA, sPxB, sPyA, sPyB, sU);
}

// -------- final: one more p-update (p49 -> p50) fused with the output --------
__global__ __launch_bounds__(256) void tv_last(const __half* __restrict__ xh,
                                               const float* __restrict__ x,
                                               const __half2* __restrict__ pi,
                                               float* __restrict__ out)
{
    __shared__ __half2 sp0[LSZ];
    __shared__ __half2 sp1[LSZ];
    __shared__ float   su [LSZ];

    const int tid  = threadIdx.x;
    const int lane = tid & 63;
    const int r0 = blockIdx.y * TH2;
    const int c0 = blockIdx.x * TW2;
    const __half2 tau2 = __float2half2_rn(TAU_F);

    int lb[3], lup[3], llf[3], ldn[3], lrt[3], gj0a[3], gofs[3];
    bool wr[3];
#pragma unroll
    for (int r = 0; r < 3; ++r) {
        int slot = tid + 256 * r;
        wr[r] = (slot < NSL);
        if (slot >= NSL) slot = NSL - 1;
        int cr = slot / NCH;
        int cc = slot - cr * NCH;
        int gi  = r0 - 2 + cr;
        int gj0 = c0 - 4 + cc * 4;
        int gic = min(max(gi, 0), HH - 1);
        int gjc = min(max(gj0, 0), WW - 4);
        gofs[r] = gic * WW + gjc;
        int l   = cr * ECC + cc * 4;
        lb[r]  = l;
        lup[r] = (cr > 0) ? l - ECC : l;
        llf[r] = (l > 0) ? l - 1 : 0;
        ldn[r] = (cr < ERR - 1) ? l + ECC : l;
        lrt[r] = min(l + 4, LSZ - 1);
        gj0a[r] = gj0;
    }

    __half2 c2[3][4];
    H2x2    xc[3];
#pragma unroll
    for (int r = 0; r < 3; ++r) {
        H2x4 v; v.f4 = *(const float4*)(pi + gofs[r]);
        xc[r].f2    = *(const float2*)(xh + gofs[r]);
        if (wr[r]) *(float4*)&sp0[lb[r]] = v.f4;
        c2[r][0] = v.h2[0]; c2[r][1] = v.h2[1];
        c2[r][2] = v.h2[2]; c2[r][3] = v.h2[3];
    }
    __syncthreads();

    float u1v[3][4];
#pragma unroll
    for (int r = 0; r < 3; ++r) {
        H2x4 up; up.f4 = *(float4*)&sp0[lup[r]];
        __half2 lf = shfl_up_h2(c2[r][3]);
        if (lane == 0) lf = sp0[llf[r]];
        float xs[4] = {__low2float(xc[r].h2[0]), __high2float(xc[r].h2[0]),
                       __low2float(xc[r].h2[1]), __high2float(xc[r].h2[1])};
        float4 w;
        float* wp = &w.x;
#pragma unroll
        for (int e = 0; e < 4; ++e) {
            __half2 cc = c2[r][e];
            __half2 le = (e == 0) ? lf : c2[r][e - 1];
            float dx = __low2float(up.h2[e]) - __low2float(cc);
            float dy = __high2float(le) - __high2float(cc);
            dy = (gj0a[r] + e > 0) ? dy : 0.f;
            float u = xs[e] - C_LAM * (dx + dy);
            u1v[r][e] = u;
            wp[e] = u;
        }
        if (wr[r]) *(float4*)&su[lb[r]] = w;
    }
    __syncthreads();

#pragma unroll
    for (int r = 0; r < 3; ++r) {
        float4 dn4 = *(float4*)&su[ldn[r]];
        float urr = __shfl_down(u1v[r][0], 1, 64);
        if (lane == 63) urr = su[lrt[r]];
        float dn[4] = {dn4.x, dn4.y, dn4.z, dn4.w};
        H2x4 w;
#pragma unroll
        for (int e = 0; e < 4; ++e) {
            float uc = u1v[r][e];
            float gx = dn[e] - uc;
            float rt = (e == 3) ? urr : u1v[r][e + 1];
            float gy = (gj0a[r] + e < WW - 1) ? (rt - uc) : 0.f;
            __half2 g = __float22half2_rn(make_float2(gx, gy));
            w.h2[e] = clamp1h2(__hfma2(g, tau2, c2[r][e]));
        }
        if (wr[r]) *(float4*)&sp1[lb[r]] = w.f4;
    }
    __syncthreads();

    // out = x - c*div(p50) on interior
#pragma unroll
    for (int r = 0; r < 2; ++r) {
        int slot = tid + 256 * r;
        int ir = slot >> 4, icc = slot & 15;
        int er = ir + 2, ec = icc * 4 + 4;
        int l  = er * ECC + ec;
        int gi = r0 + ir, gj = c0 + icc * 4;

        H2x4 pc_; pc_.f4 = *(float4*)&sp1[l];
        H2x4 pu_; pu_.f4 = *(float4*)&sp1[l - ECC];
        __half2 plf = shfl_up_h2(pc_.h2[3]);
        if ((tid & 15) == 0) plf = sp1[l - 1];

        float4 xr4 = *(const float4*)(x + (size_t)gi * WW + gj);
        float xv[4] = {xr4.x, xr4.y, xr4.z, xr4.w};
        float o[4];
#pragma unroll
        for (int e = 0; e < 4; ++e) {
            __half2 cc = pc_.h2[e];
            __half2 le = (e == 0) ? plf : pc_.h2[e - 1];
            float dx = __low2float(pu_.h2[e]) - __low2float(cc);
            dx = (gi > 0) ? dx : 0.f;
            float dy = __high2float(le) - __high2float(cc);
            dy = (gj + e > 0) ? dy : 0.f;
            o[e] = xv[e] - C_LAM * (dx + dy);
        }
        *(float4*)(out + (size_t)gi * WW + gj) = make_float4(o[0], o[1], o[2], o[3]);
    }
}

extern "C" void kernel_launch(void* const* d_in, const int* in_sizes, int n_in,
                              void* d_out, int out_size, void* d_ws, size_t ws_size,
                              hipStream_t stream)
{
    const float* x = (const float*)d_in[0];
    float* out = (float*)d_out;
    const size_t N = (size_t)HH * (size_t)WW;

    // ws layout: pA (64 MiB) | pB (64 MiB) | x_h (32 MiB)
    __half2* pA = (__half2*)d_ws;
    __half2* pB = pA + N;
    __half*  xh = (__half*)(pB + N);

    dim3 b1(BX, BY), g1(WW / TILE_W, HH / BY);
    dim3 b3(256),    g3(WW / TW2, HH / TH2);

    tv_first<<<g1, b1, 0, stream>>>(x, pA, xh);              // iter 1
    __half2 *pin = pA, *pout = pB;
    for (int p = 0; p < 16; ++p) {                           // iters 2..49 (16x3)
        tv_iter3<<<g3, b3, 0, stream>>>(xh, pin, pout);
        __half2* t = pin; pin = pout; pout = t;
    }
    tv_last<<<g3, b3, 0, stream>>>(xh, x, pin, out);         // iter 50 + output
}

// Round 11
// 594.262 us; speedup vs baseline: 1.9639x; 1.3586x over previous
//
#include <hip/hip_runtime.h>
#include <hip/hip_fp16.h>

#define HH 4096
#define WW 4096

constexpr float C_LAM = 0.1f;   // ALPHA * LAMDA
constexpr float TAU_F = 0.25f;

// ---- first-iteration kernel geometry ----
#define BX 64
#define BY 8
#define VEC 4
#define TILE_W (BX * VEC)       // 256 cols per block

// ---- tv_last (2-ring) geometry ----
#define TW2 64
#define TH2 32
#define ERR 36
#define ECC 72
#define NCH (ECC / 4)
#define NSL (ERR * NCH)         // 648
#define LSZ (ERR * ECC)         // 2592

// ---- tv_iter8 (8-step) geometry ----
#define TH8 32                  // interior rows
#define TW8 64                  // interior cols
#define ER8 48                  // rows [r0-8, r0+39]
#define EC8 80                  // cols [c0-8, c0+71] logical
#define ECP8 84                 // padded LDS row stride (halves): 21 dwords, odd
#define NCH8 20                 // 4-px chunks per row
#define NSL8 (ER8 * NCH8)       // 960 chunk-slots
#define LSZ8 (ER8 * ECP8)       // 4032 halves per plane
#define REP 4

typedef float __attribute__((ext_vector_type(4))) f32x4_t;
typedef float __attribute__((ext_vector_type(2))) f32x2_t;

union H2x4 { float4 f4; f32x4_t v4; __half2 h2[4]; unsigned u32[4]; };
union H2x2 { float2 f2; f32x2_t v2; __half2 h2[2]; unsigned u32[2]; };
union H2U  { __half2 h; unsigned int u; };

__device__ __forceinline__ float clip1(float v) {
    return fminf(1.0f, fmaxf(-1.0f, v));
}

// packed clamp to [-1,1] (no __hmax2/__hmin2 in ROCm 7.2 headers)
__device__ __forceinline__ __half2 clamp1h2(__half2 v) {
    H2U a; a.h = v;
    unsigned int lo = 0xBC00BC00u;   // (-1, -1) fp16
    unsigned int hi = 0x3C003C00u;   // (+1, +1) fp16
    unsigned int t, r;
    asm("v_pk_max_f16 %0, %1, %2" : "=v"(t) : "v"(a.u), "v"(lo));
    asm("v_pk_min_f16 %0, %1, %2" : "=v"(r) : "v"(t),   "v"(hi));
    H2U b; b.u = r;
    return b.h;
}

__device__ __forceinline__ __half2 shfl_up_h2(__half2 v) {
    H2U a; a.h = v;
    int s = __shfl_up((int)a.u, 1, 64);
    H2U b; b.u = (unsigned)s;
    return b.h;
}

// (hi:lo) >> 16, as __half2: result = (lo.hi, hi.lo)
__device__ __forceinline__ __half2 align16(__half2 hi, __half2 lo) {
    H2U a, b, d;
    a.h = hi; b.h = lo;
    asm("v_alignbit_b32 %0, %1, %2, 16" : "=v"(d.u) : "v"(a.u), "v"(b.u));
    return d.h;
}

// iteration 0 (p=0 -> u=x):  p = clip(tau * grad(x)); also emits x_h = fp16(x)
__global__ __launch_bounds__(512) void tv_first(const float* __restrict__ x,
                                                __half2* __restrict__ po,
                                                __half* __restrict__ xh)
{
    const int tx = threadIdx.x, ty = threadIdx.y;
    const int i = blockIdx.y * BY + ty;
    const int j = blockIdx.x * TILE_W + tx * VEC;
    const size_t idx = (size_t)i * WW + j;

    float4 xc4 = *(const float4*)(x + idx);
    float4 xd4 = make_float4(0.f, 0.f, 0.f, 0.f);
    if (i < HH - 1) xd4 = *(const float4*)(x + idx + WW);

    float c[4] = {xc4.x, xc4.y, xc4.z, xc4.w};
    float d[4] = {xd4.x, xd4.y, xd4.z, xd4.w};

    float xr = __shfl_down(c[0], 1, 64);
    if (tx == BX - 1 && j + VEC < WW) xr = x[idx + VEC];

    H2x4 o;
#pragma unroll
    for (int e = 0; e < 4; ++e) {
        float gx = (i < HH - 1) ? (d[e] - c[e]) : 0.f;
        float rn = (e < 3) ? c[e + 1] : xr;
        float gy = (j + e < WW - 1) ? (rn - c[e]) : 0.f;
        o.h2[e] = __floats2half2_rn(clip1(TAU_F * gx), clip1(TAU_F * gy));
    }
    *(float4*)(po + idx) = o.f4;

    H2x2 xs;
    xs.h2[0] = __floats2half2_rn(c[0], c[1]);
    xs.h2[1] = __floats2half2_rn(c[2], c[3]);
    *(float2*)(xh + idx) = xs.f2;
}

// -------- eight fused Chambolle steps per pass, packed fp16 SoA --------
// Key structural point: the p-stage never READS the p planes from LDS (own p
// is in registers), so px/py are updated IN PLACE -> only 3 LDS planes
// (px, py, u), 24.2 KB, 6 blocks/CU. Row stride padded to 21 dwords (odd) so
// b64 chunk reads spread banks. Per-iteration math identical to R10.
template<bool EDGE>
__device__ __forceinline__ void iter8_body(const __half* __restrict__ xh,
                                           const __half2* __restrict__ pi,
                                           __half2* __restrict__ po,
                                           __half* sPx, __half* sPy, __half* sU)
{
    const int tid = threadIdx.x;
    const int r0 = blockIdx.y * TH8;
    const int c0 = blockIdx.x * TW8;
    const __half2 tau2 = __float2half2_rn(TAU_F);
    const __half2 nC2  = __float2half2_rn(-C_LAM);
    const unsigned SEL0 = 0x05040100u, SEL1 = 0x07060302u;

    int lb[REP], lup[REP], llf[REP], ldn[REP], lrt[REP], gw[REP];
    unsigned mdy[REP], mgy[REP];
    bool wr[REP], wout[REP], bdx[REP], bgx[REP];
    __half2 X[REP][2], Y[REP][2], XH[REP][2], U[REP][2];

    // ---- setup + stage A: load interleaved p + xh; deinterleave; stage ----
#pragma unroll
    for (int r = 0; r < REP; ++r) {
        int slot = tid + 256 * r;
        wr[r] = (slot < NSL8);
        if (!wr[r]) slot = NSL8 - 1;          // dup slot: writes masked
        int cr = slot / NCH8;
        int cc = slot - cr * NCH8;
        int gi  = r0 - 8 + cr;
        int gj0 = c0 - 8 + cc * 4;
        int gic = min(max(gi, 0), HH - 1);
        int gjc = min(max(gj0, 0), WW - 4);
        int gofs = gic * WW + gjc;
        int l = cr * ECP8 + cc * 4;
        lb[r]  = l;
        lup[r] = (cr > 0)        ? l - ECP8 : l;   // clamp: garbage-safe ring
        llf[r] = (cc > 0)        ? l - 4    : l;
        ldn[r] = (cr < ER8 - 1)  ? l + ECP8 : l;
        lrt[r] = (cc < NCH8 - 1) ? l + 4    : l;
        bdx[r] = (gi > 0);
        bgx[r] = (gi < HH - 1);
        mdy[r] = (gj0 == 0)      ? 0xFFFF0000u : 0xFFFFFFFFu;  // zero dy at j=0
        mgy[r] = (gj0 + 4 == WW) ? 0x0000FFFFu : 0xFFFFFFFFu;  // zero gy at j=WW-1
        wout[r] = wr[r] && (cr >= 8) && (cr < 8 + TH8) && (cc >= 2) && (cc < 18);
        gw[r] = gi * WW + gj0;

        H2x4 v;  v.v4  = *(const f32x4_t*)(pi + gofs);
        H2x2 xs; xs.v2 = *(const f32x2_t*)(xh + gofs);
        H2U xa, xb, ya, yb;
        asm("v_perm_b32 %0, %1, %2, %3" : "=v"(xa.u) : "v"(v.u32[1]), "v"(v.u32[0]), "v"(SEL0));
        asm("v_perm_b32 %0, %1, %2, %3" : "=v"(ya.u) : "v"(v.u32[1]), "v"(v.u32[0]), "v"(SEL1));
        asm("v_perm_b32 %0, %1, %2, %3" : "=v"(xb.u) : "v"(v.u32[3]), "v"(v.u32[2]), "v"(SEL0));
        asm("v_perm_b32 %0, %1, %2, %3" : "=v"(yb.u) : "v"(v.u32[3]), "v"(v.u32[2]), "v"(SEL1));
        X[r][0] = xa.h; X[r][1] = xb.h;
        Y[r][0] = ya.h; Y[r][1] = yb.h;
        XH[r][0] = xs.h2[0]; XH[r][1] = xs.h2[1];
        if (wr[r]) {
            H2x2 wx; wx.h2[0] = X[r][0]; wx.h2[1] = X[r][1];
            *(f32x2_t*)(sPx + l) = wx.v2;
            H2x2 wy; wy.h2[0] = Y[r][0]; wy.h2[1] = Y[r][1];
            *(f32x2_t*)(sPy + l) = wy.v2;
        }
    }
    __syncthreads();

    // u = xh - C*div(p):  dx = px(up) - px, dy = left-shifted py - py
    auto ustage = [&]() {
#pragma unroll
        for (int r = 0; r < REP; ++r) {
            H2x2 up; up.v2 = *(const f32x2_t*)(sPx + lup[r]);
            H2x2 lf; lf.v2 = *(const f32x2_t*)(sPy + llf[r]);
            __half2 zm0 = align16(Y[r][0], lf.h2[1]);  // (pyL3, py0)
            __half2 zm1 = align16(Y[r][1], Y[r][0]);   // (py1, py2)
            __half2 dx0 = __hsub2(up.h2[0], X[r][0]);
            __half2 dx1 = __hsub2(up.h2[1], X[r][1]);
            __half2 dy0 = __hsub2(zm0, Y[r][0]);
            __half2 dy1 = __hsub2(zm1, Y[r][1]);
            if (EDGE) {
                H2U z; z.u = 0u;
                if (!bdx[r]) { dx0 = z.h; dx1 = z.h; }
                H2U a; a.h = dy0; a.u &= mdy[r]; dy0 = a.h;
            }
            U[r][0] = __hfma2(__hadd2(dx0, dy0), nC2, XH[r][0]);
            U[r][1] = __hfma2(__hadd2(dx1, dy1), nC2, XH[r][1]);
            if (wr[r]) {
                H2x2 w; w.h2[0] = U[r][0]; w.h2[1] = U[r][1];
                *(f32x2_t*)(sU + lb[r]) = w.v2;
            }
        }
    };

    // p = clip(p + tau*grad(u)):  gx = u(down) - u, gy = right-shifted u - u
    auto pstage_lds = [&]() {
#pragma unroll
        for (int r = 0; r < REP; ++r) {
            H2x2 dn; dn.v2 = *(const f32x2_t*)(sU + ldn[r]);
            H2x2 rt; rt.v2 = *(const f32x2_t*)(sU + lrt[r]);
            __half2 zp0 = align16(U[r][1], U[r][0]);   // (u1, u2)
            __half2 zp1 = align16(rt.h2[0], U[r][1]);  // (u3, r0)
            __half2 gx0 = __hsub2(dn.h2[0], U[r][0]);
            __half2 gx1 = __hsub2(dn.h2[1], U[r][1]);
            __half2 gy0 = __hsub2(zp0, U[r][0]);
            __half2 gy1 = __hsub2(zp1, U[r][1]);
            if (EDGE) {
                H2U z; z.u = 0u;
                if (!bgx[r]) { gx0 = z.h; gx1 = z.h; }
                H2U a; a.h = gy1; a.u &= mgy[r]; gy1 = a.h;
            }
            X[r][0] = clamp1h2(__hfma2(gx0, tau2, X[r][0]));
            X[r][1] = clamp1h2(__hfma2(gx1, tau2, X[r][1]));
            Y[r][0] = clamp1h2(__hfma2(gy0, tau2, Y[r][0]));
            Y[r][1] = clamp1h2(__hfma2(gy1, tau2, Y[r][1]));
            if (wr[r]) {                       // in-place p update (no reader)
                H2x2 wx; wx.h2[0] = X[r][0]; wx.h2[1] = X[r][1];
                *(f32x2_t*)(sPx + lb[r]) = wx.v2;
                H2x2 wy; wy.h2[0] = Y[r][0]; wy.h2[1] = Y[r][1];
                *(f32x2_t*)(sPy + lb[r]) = wy.v2;
            }
        }
    };

    auto pstage_out = [&]() {
#pragma unroll
        for (int r = 0; r < REP; ++r) {
            H2x2 dn; dn.v2 = *(const f32x2_t*)(sU + ldn[r]);
            H2x2 rt; rt.v2 = *(const f32x2_t*)(sU + lrt[r]);
            __half2 zp0 = align16(U[r][1], U[r][0]);
            __half2 zp1 = align16(rt.h2[0], U[r][1]);
            __half2 gx0 = __hsub2(dn.h2[0], U[r][0]);
            __half2 gx1 = __hsub2(dn.h2[1], U[r][1]);
            __half2 gy0 = __hsub2(zp0, U[r][0]);
            __half2 gy1 = __hsub2(zp1, U[r][1]);
            if (EDGE) {
                H2U z; z.u = 0u;
                if (!bgx[r]) { gx0 = z.h; gx1 = z.h; }
                H2U a; a.h = gy1; a.u &= mgy[r]; gy1 = a.h;
            }
            __half2 x0 = clamp1h2(__hfma2(gx0, tau2, X[r][0]));
            __half2 x1 = clamp1h2(__hfma2(gx1, tau2, X[r][1]));
            __half2 y0 = clamp1h2(__hfma2(gy0, tau2, Y[r][0]));
            __half2 y1 = clamp1h2(__hfma2(gy1, tau2, Y[r][1]));
            if (wout[r]) {
                H2U xx0, xx1, yy0, yy1;
                xx0.h = x0; xx1.h = x1; yy0.h = y0; yy1.h = y1;
                H2x4 w;
                asm("v_perm_b32 %0, %1, %2, %3" : "=v"(w.u32[0]) : "v"(yy0.u), "v"(xx0.u), "v"(SEL0));
                asm("v_perm_b32 %0, %1, %2, %3" : "=v"(w.u32[1]) : "v"(yy0.u), "v"(xx0.u), "v"(SEL1));
                asm("v_perm_b32 %0, %1, %2, %3" : "=v"(w.u32[2]) : "v"(yy1.u), "v"(xx1.u), "v"(SEL0));
                asm("v_perm_b32 %0, %1, %2, %3" : "=v"(w.u32[3]) : "v"(yy1.u), "v"(xx1.u), "v"(SEL1));
                *(f32x4_t*)(po + gw[r]) = w.v4;
            }
        }
    };

    for (int k = 0; k < 7; ++k) {
        ustage(); __syncthreads();
        pstage_lds(); __syncthreads();
    }
    ustage(); __syncthreads();
    pstage_out();
}

__global__ __launch_bounds__(256) void tv_iter8(const __half* __restrict__ xh,
                                                const __half2* __restrict__ pi,
                                                __half2* __restrict__ po)
{
    __shared__ __align__(16) __half sPx[LSZ8];
    __shared__ __align__(16) __half sPy[LSZ8];
    __shared__ __align__(16) __half sU[LSZ8];

    const bool edge = (blockIdx.x == 0) || (blockIdx.x == gridDim.x - 1) ||
                      (blockIdx.y == 0) || (blockIdx.y == gridDim.y - 1);
    if (!edge) iter8_body<false>(xh, pi, po, sPx, sPy, sU);
    else       iter8_body<true >(xh, pi, po, sPx, sPy, sU);
}

// -------- final: one more p-update (p49 -> p50) fused with the output --------
__global__ __launch_bounds__(256) void tv_last(const __half* __restrict__ xh,
                                               const float* __restrict__ x,
                                               const __half2* __restrict__ pi,
                                               float* __restrict__ out)
{
    __shared__ __half2 sp0[LSZ];
    __shared__ __half2 sp1[LSZ];
    __shared__ float   su [LSZ];

    const int tid  = threadIdx.x;
    const int lane = tid & 63;
    const int r0 = blockIdx.y * TH2;
    const int c0 = blockIdx.x * TW2;
    const __half2 tau2 = __float2half2_rn(TAU_F);

    int lb[3], lup[3], llf[3], ldn[3], lrt[3], gj0a[3], gofs[3];
    bool wr[3];
#pragma unroll
    for (int r = 0; r < 3; ++r) {
        int slot = tid + 256 * r;
        wr[r] = (slot < NSL);
        if (slot >= NSL) slot = NSL - 1;
        int cr = slot / NCH;
        int cc = slot - cr * NCH;
        int gi  = r0 - 2 + cr;
        int gj0 = c0 - 4 + cc * 4;
        int gic = min(max(gi, 0), HH - 1);
        int gjc = min(max(gj0, 0), WW - 4);
        gofs[r] = gic * WW + gjc;
        int l   = cr * ECC + cc * 4;
        lb[r]  = l;
        lup[r] = (cr > 0) ? l - ECC : l;
        llf[r] = (l > 0) ? l - 1 : 0;
        ldn[r] = (cr < ERR - 1) ? l + ECC : l;
        lrt[r] = min(l + 4, LSZ - 1);
        gj0a[r] = gj0;
    }

    __half2 c2[3][4];
    H2x2    xc[3];
#pragma unroll
    for (int r = 0; r < 3; ++r) {
        H2x4 v; v.f4 = *(const float4*)(pi + gofs[r]);
        xc[r].f2    = *(const float2*)(xh + gofs[r]);
        if (wr[r]) *(float4*)&sp0[lb[r]] = v.f4;
        c2[r][0] = v.h2[0]; c2[r][1] = v.h2[1];
        c2[r][2] = v.h2[2]; c2[r][3] = v.h2[3];
    }
    __syncthreads();

    float u1v[3][4];
#pragma unroll
    for (int r = 0; r < 3; ++r) {
        H2x4 up; up.f4 = *(float4*)&sp0[lup[r]];
        __half2 lf = shfl_up_h2(c2[r][3]);
        if (lane == 0) lf = sp0[llf[r]];
        float xs[4] = {__low2float(xc[r].h2[0]), __high2float(xc[r].h2[0]),
                       __low2float(xc[r].h2[1]), __high2float(xc[r].h2[1])};
        float4 w;
        float* wp = &w.x;
#pragma unroll
        for (int e = 0; e < 4; ++e) {
            __half2 cc = c2[r][e];
            __half2 le = (e == 0) ? lf : c2[r][e - 1];
            float dx = __low2float(up.h2[e]) - __low2float(cc);
            float dy = __high2float(le) - __high2float(cc);
            dy = (gj0a[r] + e > 0) ? dy : 0.f;
            float u = xs[e] - C_LAM * (dx + dy);
            u1v[r][e] = u;
            wp[e] = u;
        }
        if (wr[r]) *(float4*)&su[lb[r]] = w;
    }
    __syncthreads();

#pragma unroll
    for (int r = 0; r < 3; ++r) {
        float4 dn4 = *(float4*)&su[ldn[r]];
        float urr = __shfl_down(u1v[r][0], 1, 64);
        if (lane == 63) urr = su[lrt[r]];
        float dn[4] = {dn4.x, dn4.y, dn4.z, dn4.w};
        H2x4 w;
#pragma unroll
        for (int e = 0; e < 4; ++e) {
            float uc = u1v[r][e];
            float gx = dn[e] - uc;
            float rt = (e == 3) ? urr : u1v[r][e + 1];
            float gy = (gj0a[r] + e < WW - 1) ? (rt - uc) : 0.f;
            __half2 g = __float22half2_rn(make_float2(gx, gy));
            w.h2[e] = clamp1h2(__hfma2(g, tau2, c2[r][e]));
        }
        if (wr[r]) *(float4*)&sp1[lb[r]] = w.f4;
    }
    __syncthreads();

    // out = x - c*div(p50) on interior
#pragma unroll
    for (int r = 0; r < 2; ++r) {
        int slot = tid + 256 * r;
        int ir = slot >> 4, icc = slot & 15;
        int er = ir + 2, ec = icc * 4 + 4;
        int l  = er * ECC + ec;
        int gi = r0 + ir, gj = c0 + icc * 4;

        H2x4 pc_; pc_.f4 = *(float4*)&sp1[l];
        H2x4 pu_; pu_.f4 = *(float4*)&sp1[l - ECC];
        __half2 plf = shfl_up_h2(pc_.h2[3]);
        if ((tid & 15) == 0) plf = sp1[l - 1];

        float4 xr4 = *(const float4*)(x + (size_t)gi * WW + gj);
        float xv[4] = {xr4.x, xr4.y, xr4.z, xr4.w};
        float o[4];
#pragma unroll
        for (int e = 0; e < 4; ++e) {
            __half2 cc = pc_.h2[e];
            __half2 le = (e == 0) ? plf : pc_.h2[e - 1];
            float dx = __low2float(pu_.h2[e]) - __low2float(cc);
            dx = (gi > 0) ? dx : 0.f;
            float dy = __high2float(le) - __high2float(cc);
            dy = (gj + e > 0) ? dy : 0.f;
            o[e] = xv[e] - C_LAM * (dx + dy);
        }
        *(float4*)(out + (size_t)gi * WW + gj) = make_float4(o[0], o[1], o[2], o[3]);
    }
}

extern "C" void kernel_launch(void* const* d_in, const int* in_sizes, int n_in,
                              void* d_out, int out_size, void* d_ws, size_t ws_size,
                              hipStream_t stream)
{
    const float* x = (const float*)d_in[0];
    float* out = (float*)d_out;
    const size_t N = (size_t)HH * (size_t)WW;

    // ws layout: pA (64 MiB) | pB (64 MiB) | x_h (32 MiB)
    __half2* pA = (__half2*)d_ws;
    __half2* pB = pA + N;
    __half*  xh = (__half*)(pB + N);

    dim3 b1(BX, BY), g1(WW / TILE_W, HH / BY);
    dim3 b8(256),    g8(WW / TW8, HH / TH8);
    dim3 bL(256),    gL(WW / TW2, HH / TH2);

    tv_first<<<g1, b1, 0, stream>>>(x, pA, xh);              // iter 1
    __half2 *pin = pA, *pout = pB;
    for (int p = 0; p < 6; ++p) {                            // iters 2..49 (6x8)
        tv_iter8<<<g8, b8, 0, stream>>>(xh, pin, pout);
        __half2* t = pin; pin = pout; pout = t;
    }
    tv_last<<<gL, bL, 0, stream>>>(xh, x, pin, out);         // iter 50 + output
}

// Round 12
// 574.962 us; speedup vs baseline: 2.0298x; 1.0336x over previous
//
#include <hip/hip_runtime.h>
#include <hip/hip_fp16.h>

#define HH 4096
#define WW 4096

constexpr float C_LAM = 0.1f;   // ALPHA * LAMDA
constexpr float TAU_F = 0.25f;

// ---- first-iteration kernel geometry ----
#define BX 64
#define BY 8
#define VEC 4
#define TILE_W (BX * VEC)       // 256 cols per block

// ---- tv_last (2-ring) geometry ----
#define TW2 64
#define TH2 32
#define ERR 36
#define ECC 72
#define NCH (ECC / 4)
#define NSL (ERR * NCH)         // 648
#define LSZ (ERR * ECC)         // 2592

// ---- tv_iter8 (8-step) geometry ----
// CRITICAL: row stride == logical cols == NCH8*4 (NO padding). Consecutive
// chunk-slots then form one contiguous dword-pair array, so a wave's 64
// consecutive b64 LDS accesses load every bank exactly 4x (zero conflicts,
// the R10 property). R11's pad-to-84 broke this -> 17M conflict cycles.
#define TH8 32                  // interior rows
#define TW8 64                  // interior cols
#define ER8 48                  // rows [r0-8, r0+39]
#define EC8 80                  // cols [c0-8, c0+71]
#define ECP8 80                 // row stride in halves == EC8 (contiguous!)
#define NCH8 20                 // 4-px chunks per row
#define NSL8 (ER8 * NCH8)       // 960 chunk-slots
#define LSZ8 (ER8 * ECP8)       // 3840 halves per plane (7.5 KB)
#define REP 4

typedef float __attribute__((ext_vector_type(4))) f32x4_t;
typedef float __attribute__((ext_vector_type(2))) f32x2_t;

union H2x4 { float4 f4; f32x4_t v4; __half2 h2[4]; unsigned u32[4]; };
union H2x2 { float2 f2; f32x2_t v2; __half2 h2[2]; unsigned u32[2]; };
union H2U  { __half2 h; unsigned int u; };

__device__ __forceinline__ float clip1(float v) {
    return fminf(1.0f, fmaxf(-1.0f, v));
}

// packed clamp to [-1,1] (no __hmax2/__hmin2 in ROCm 7.2 headers)
__device__ __forceinline__ __half2 clamp1h2(__half2 v) {
    H2U a; a.h = v;
    unsigned int lo = 0xBC00BC00u;   // (-1, -1) fp16
    unsigned int hi = 0x3C003C00u;   // (+1, +1) fp16
    unsigned int t, r;
    asm("v_pk_max_f16 %0, %1, %2" : "=v"(t) : "v"(a.u), "v"(lo));
    asm("v_pk_min_f16 %0, %1, %2" : "=v"(r) : "v"(t),   "v"(hi));
    H2U b; b.u = r;
    return b.h;
}

__device__ __forceinline__ __half2 shfl_up_h2(__half2 v) {
    H2U a; a.h = v;
    int s = __shfl_up((int)a.u, 1, 64);
    H2U b; b.u = (unsigned)s;
    return b.h;
}

// (hi:lo) >> 16, as __half2: result = (lo.hi, hi.lo)
__device__ __forceinline__ __half2 align16(__half2 hi, __half2 lo) {
    H2U a, b, d;
    a.h = hi; b.h = lo;
    asm("v_alignbit_b32 %0, %1, %2, 16" : "=v"(d.u) : "v"(a.u), "v"(b.u));
    return d.h;
}

// iteration 0 (p=0 -> u=x):  p = clip(tau * grad(x)); also emits x_h = fp16(x)
__global__ __launch_bounds__(512) void tv_first(const float* __restrict__ x,
                                                __half2* __restrict__ po,
                                                __half* __restrict__ xh)
{
    const int tx = threadIdx.x, ty = threadIdx.y;
    const int i = blockIdx.y * BY + ty;
    const int j = blockIdx.x * TILE_W + tx * VEC;
    const size_t idx = (size_t)i * WW + j;

    float4 xc4 = *(const float4*)(x + idx);
    float4 xd4 = make_float4(0.f, 0.f, 0.f, 0.f);
    if (i < HH - 1) xd4 = *(const float4*)(x + idx + WW);

    float c[4] = {xc4.x, xc4.y, xc4.z, xc4.w};
    float d[4] = {xd4.x, xd4.y, xd4.z, xd4.w};

    float xr = __shfl_down(c[0], 1, 64);
    if (tx == BX - 1 && j + VEC < WW) xr = x[idx + VEC];

    H2x4 o;
#pragma unroll
    for (int e = 0; e < 4; ++e) {
        float gx = (i < HH - 1) ? (d[e] - c[e]) : 0.f;
        float rn = (e < 3) ? c[e + 1] : xr;
        float gy = (j + e < WW - 1) ? (rn - c[e]) : 0.f;
        o.h2[e] = __floats2half2_rn(clip1(TAU_F * gx), clip1(TAU_F * gy));
    }
    *(float4*)(po + idx) = o.f4;

    H2x2 xs;
    xs.h2[0] = __floats2half2_rn(c[0], c[1]);
    xs.h2[1] = __floats2half2_rn(c[2], c[3]);
    *(float2*)(xh + idx) = xs.f2;
}

// -------- eight fused Chambolle steps per pass, packed fp16 SoA --------
// p-stage never READS p planes from LDS (own p in regs) -> px/py updated
// IN PLACE -> 3 planes only (px, py, u) = 22.5 KB, 6 blocks/CU.
template<bool EDGE>
__device__ __forceinline__ void iter8_body(const __half* __restrict__ xh,
                                           const __half2* __restrict__ pi,
                                           __half2* __restrict__ po,
                                           __half* sPx, __half* sPy, __half* sU)
{
    const int tid = threadIdx.x;
    const int r0 = blockIdx.y * TH8;
    const int c0 = blockIdx.x * TW8;
    const __half2 tau2 = __float2half2_rn(TAU_F);
    const __half2 nC2  = __float2half2_rn(-C_LAM);
    const unsigned SEL0 = 0x05040100u, SEL1 = 0x07060302u;

    int lb[REP], lup[REP], llf[REP], ldn[REP], lrt[REP], gw[REP];
    unsigned mdy[REP], mgy[REP];
    bool wr[REP], wout[REP], bdx[REP], bgx[REP];
    __half2 X[REP][2], Y[REP][2], XH[REP][2], U[REP][2];

    // ---- setup + stage A: load interleaved p + xh; deinterleave; stage ----
#pragma unroll
    for (int r = 0; r < REP; ++r) {
        int slot = tid + 256 * r;
        wr[r] = (slot < NSL8);
        if (!wr[r]) slot = NSL8 - 1;          // dup slot: writes masked
        int cr = slot / NCH8;
        int cc = slot - cr * NCH8;
        int gi  = r0 - 8 + cr;
        int gj0 = c0 - 8 + cc * 4;
        int gic = min(max(gi, 0), HH - 1);
        int gjc = min(max(gj0, 0), WW - 4);
        int gofs = gic * WW + gjc;
        int l = cr * ECP8 + cc * 4;
        lb[r]  = l;
        lup[r] = (cr > 0)        ? l - ECP8 : l;   // clamp: garbage-safe ring
        llf[r] = (cc > 0)        ? l - 4    : l;
        ldn[r] = (cr < ER8 - 1)  ? l + ECP8 : l;
        lrt[r] = (cc < NCH8 - 1) ? l + 4    : l;
        bdx[r] = (gi > 0);
        bgx[r] = (gi < HH - 1);
        mdy[r] = (gj0 == 0)      ? 0xFFFF0000u : 0xFFFFFFFFu;  // zero dy at j=0
        mgy[r] = (gj0 + 4 == WW) ? 0x0000FFFFu : 0xFFFFFFFFu;  // zero gy at j=WW-1
        wout[r] = wr[r] && (cr >= 8) && (cr < 8 + TH8) && (cc >= 2) && (cc < 18);
        gw[r] = gi * WW + gj0;

        H2x4 v;  v.v4  = *(const f32x4_t*)(pi + gofs);
        H2x2 xs; xs.v2 = *(const f32x2_t*)(xh + gofs);
        H2U xa, xb, ya, yb;
        asm("v_perm_b32 %0, %1, %2, %3" : "=v"(xa.u) : "v"(v.u32[1]), "v"(v.u32[0]), "v"(SEL0));
        asm("v_perm_b32 %0, %1, %2, %3" : "=v"(ya.u) : "v"(v.u32[1]), "v"(v.u32[0]), "v"(SEL1));
        asm("v_perm_b32 %0, %1, %2, %3" : "=v"(xb.u) : "v"(v.u32[3]), "v"(v.u32[2]), "v"(SEL0));
        asm("v_perm_b32 %0, %1, %2, %3" : "=v"(yb.u) : "v"(v.u32[3]), "v"(v.u32[2]), "v"(SEL1));
        X[r][0] = xa.h; X[r][1] = xb.h;
        Y[r][0] = ya.h; Y[r][1] = yb.h;
        XH[r][0] = xs.h2[0]; XH[r][1] = xs.h2[1];
        if (wr[r]) {
            H2x2 wx; wx.h2[0] = X[r][0]; wx.h2[1] = X[r][1];
            *(f32x2_t*)(sPx + l) = wx.v2;
            H2x2 wy; wy.h2[0] = Y[r][0]; wy.h2[1] = Y[r][1];
            *(f32x2_t*)(sPy + l) = wy.v2;
        }
    }
    __syncthreads();

    // u = xh - C*div(p):  dx = px(up) - px, dy = left-shifted py - py
    auto ustage = [&]() {
#pragma unroll
        for (int r = 0; r < REP; ++r) {
            H2x2 up; up.v2 = *(const f32x2_t*)(sPx + lup[r]);
            H2x2 lf; lf.v2 = *(const f32x2_t*)(sPy + llf[r]);
            __half2 zm0 = align16(Y[r][0], lf.h2[1]);  // (pyL3, py0)
            __half2 zm1 = align16(Y[r][1], Y[r][0]);   // (py1, py2)
            __half2 dx0 = __hsub2(up.h2[0], X[r][0]);
            __half2 dx1 = __hsub2(up.h2[1], X[r][1]);
            __half2 dy0 = __hsub2(zm0, Y[r][0]);
            __half2 dy1 = __hsub2(zm1, Y[r][1]);
            if (EDGE) {
                H2U z; z.u = 0u;
                if (!bdx[r]) { dx0 = z.h; dx1 = z.h; }
                H2U a; a.h = dy0; a.u &= mdy[r]; dy0 = a.h;
            }
            U[r][0] = __hfma2(__hadd2(dx0, dy0), nC2, XH[r][0]);
            U[r][1] = __hfma2(__hadd2(dx1, dy1), nC2, XH[r][1]);
            if (wr[r]) {
                H2x2 w; w.h2[0] = U[r][0]; w.h2[1] = U[r][1];
                *(f32x2_t*)(sU + lb[r]) = w.v2;
            }
        }
    };

    // p = clip(p + tau*grad(u)):  gx = u(down) - u, gy = right-shifted u - u
    auto pstage_lds = [&]() {
#pragma unroll
        for (int r = 0; r < REP; ++r) {
            H2x2 dn; dn.v2 = *(const f32x2_t*)(sU + ldn[r]);
            H2x2 rt; rt.v2 = *(const f32x2_t*)(sU + lrt[r]);
            __half2 zp0 = align16(U[r][1], U[r][0]);   // (u1, u2)
            __half2 zp1 = align16(rt.h2[0], U[r][1]);  // (u3, r0)
            __half2 gx0 = __hsub2(dn.h2[0], U[r][0]);
            __half2 gx1 = __hsub2(dn.h2[1], U[r][1]);
            __half2 gy0 = __hsub2(zp0, U[r][0]);
            __half2 gy1 = __hsub2(zp1, U[r][1]);
            if (EDGE) {
                H2U z; z.u = 0u;
                if (!bgx[r]) { gx0 = z.h; gx1 = z.h; }
                H2U a; a.h = gy1; a.u &= mgy[r]; gy1 = a.h;
            }
            X[r][0] = clamp1h2(__hfma2(gx0, tau2, X[r][0]));
            X[r][1] = clamp1h2(__hfma2(gx1, tau2, X[r][1]));
            Y[r][0] = clamp1h2(__hfma2(gy0, tau2, Y[r][0]));
            Y[r][1] = clamp1h2(__hfma2(gy1, tau2, Y[r][1]));
            if (wr[r]) {                       // in-place p update (no reader)
                H2x2 wx; wx.h2[0] = X[r][0]; wx.h2[1] = X[r][1];
                *(f32x2_t*)(sPx + lb[r]) = wx.v2;
                H2x2 wy; wy.h2[0] = Y[r][0]; wy.h2[1] = Y[r][1];
                *(f32x2_t*)(sPy + lb[r]) = wy.v2;
            }
        }
    };

    auto pstage_out = [&]() {
#pragma unroll
        for (int r = 0; r < REP; ++r) {
            H2x2 dn; dn.v2 = *(const f32x2_t*)(sU + ldn[r]);
            H2x2 rt; rt.v2 = *(const f32x2_t*)(sU + lrt[r]);
            __half2 zp0 = align16(U[r][1], U[r][0]);
            __half2 zp1 = align16(rt.h2[0], U[r][1]);
            __half2 gx0 = __hsub2(dn.h2[0], U[r][0]);
            __half2 gx1 = __hsub2(dn.h2[1], U[r][1]);
            __half2 gy0 = __hsub2(zp0, U[r][0]);
            __half2 gy1 = __hsub2(zp1, U[r][1]);
            if (EDGE) {
                H2U z; z.u = 0u;
                if (!bgx[r]) { gx0 = z.h; gx1 = z.h; }
                H2U a; a.h = gy1; a.u &= mgy[r]; gy1 = a.h;
            }
            __half2 x0 = clamp1h2(__hfma2(gx0, tau2, X[r][0]));
            __half2 x1 = clamp1h2(__hfma2(gx1, tau2, X[r][1]));
            __half2 y0 = clamp1h2(__hfma2(gy0, tau2, Y[r][0]));
            __half2 y1 = clamp1h2(__hfma2(gy1, tau2, Y[r][1]));
            if (wout[r]) {
                H2U xx0, xx1, yy0, yy1;
                xx0.h = x0; xx1.h = x1; yy0.h = y0; yy1.h = y1;
                H2x4 w;
                asm("v_perm_b32 %0, %1, %2, %3" : "=v"(w.u32[0]) : "v"(yy0.u), "v"(xx0.u), "v"(SEL0));
                asm("v_perm_b32 %0, %1, %2, %3" : "=v"(w.u32[1]) : "v"(yy0.u), "v"(xx0.u), "v"(SEL1));
                asm("v_perm_b32 %0, %1, %2, %3" : "=v"(w.u32[2]) : "v"(yy1.u), "v"(xx1.u), "v"(SEL0));
                asm("v_perm_b32 %0, %1, %2, %3" : "=v"(w.u32[3]) : "v"(yy1.u), "v"(xx1.u), "v"(SEL1));
                *(f32x4_t*)(po + gw[r]) = w.v4;
            }
        }
    };

    for (int k = 0; k < 7; ++k) {
        ustage(); __syncthreads();
        pstage_lds(); __syncthreads();
    }
    ustage(); __syncthreads();
    pstage_out();
}

__global__ __launch_bounds__(256) void tv_iter8(const __half* __restrict__ xh,
                                                const __half2* __restrict__ pi,
                                                __half2* __restrict__ po)
{
    __shared__ __align__(16) __half sPx[LSZ8];
    __shared__ __align__(16) __half sPy[LSZ8];
    __shared__ __align__(16) __half sU[LSZ8];

    const bool edge = (blockIdx.x == 0) || (blockIdx.x == gridDim.x - 1) ||
                      (blockIdx.y == 0) || (blockIdx.y == gridDim.y - 1);
    if (!edge) iter8_body<false>(xh, pi, po, sPx, sPy, sU);
    else       iter8_body<true >(xh, pi, po, sPx, sPy, sU);
}

// -------- final: one more p-update (p49 -> p50) fused with the output --------
__global__ __launch_bounds__(256) void tv_last(const __half* __restrict__ xh,
                                               const float* __restrict__ x,
                                               const __half2* __restrict__ pi,
                                               float* __restrict__ out)
{
    __shared__ __half2 sp0[LSZ];
    __shared__ __half2 sp1[LSZ];
    __shared__ float   su [LSZ];

    const int tid  = threadIdx.x;
    const int lane = tid & 63;
    const int r0 = blockIdx.y * TH2;
    const int c0 = blockIdx.x * TW2;
    const __half2 tau2 = __float2half2_rn(TAU_F);

    int lb[3], lup[3], llf[3], ldn[3], lrt[3], gj0a[3], gofs[3];
    bool wr[3];
#pragma unroll
    for (int r = 0; r < 3; ++r) {
        int slot = tid + 256 * r;
        wr[r] = (slot < NSL);
        if (slot >= NSL) slot = NSL - 1;
        int cr = slot / NCH;
        int cc = slot - cr * NCH;
        int gi  = r0 - 2 + cr;
        int gj0 = c0 - 4 + cc * 4;
        int gic = min(max(gi, 0), HH - 1);
        int gjc = min(max(gj0, 0), WW - 4);
        gofs[r] = gic * WW + gjc;
        int l   = cr * ECC + cc * 4;
        lb[r]  = l;
        lup[r] = (cr > 0) ? l - ECC : l;
        llf[r] = (l > 0) ? l - 1 : 0;
        ldn[r] = (cr < ERR - 1) ? l + ECC : l;
        lrt[r] = min(l + 4, LSZ - 1);
        gj0a[r] = gj0;
    }

    __half2 c2[3][4];
    H2x2    xc[3];
#pragma unroll
    for (int r = 0; r < 3; ++r) {
        H2x4 v; v.f4 = *(const float4*)(pi + gofs[r]);
        xc[r].f2    = *(const float2*)(xh + gofs[r]);
        if (wr[r]) *(float4*)&sp0[lb[r]] = v.f4;
        c2[r][0] = v.h2[0]; c2[r][1] = v.h2[1];
        c2[r][2] = v.h2[2]; c2[r][3] = v.h2[3];
    }
    __syncthreads();

    float u1v[3][4];
#pragma unroll
    for (int r = 0; r < 3; ++r) {
        H2x4 up; up.f4 = *(float4*)&sp0[lup[r]];
        __half2 lf = shfl_up_h2(c2[r][3]);
        if (lane == 0) lf = sp0[llf[r]];
        float xs[4] = {__low2float(xc[r].h2[0]), __high2float(xc[r].h2[0]),
                       __low2float(xc[r].h2[1]), __high2float(xc[r].h2[1])};
        float4 w;
        float* wp = &w.x;
#pragma unroll
        for (int e = 0; e < 4; ++e) {
            __half2 cc = c2[r][e];
            __half2 le = (e == 0) ? lf : c2[r][e - 1];
            float dx = __low2float(up.h2[e]) - __low2float(cc);
            float dy = __high2float(le) - __high2float(cc);
            dy = (gj0a[r] + e > 0) ? dy : 0.f;
            float u = xs[e] - C_LAM * (dx + dy);
            u1v[r][e] = u;
            wp[e] = u;
        }
        if (wr[r]) *(float4*)&su[lb[r]] = w;
    }
    __syncthreads();

#pragma unroll
    for (int r = 0; r < 3; ++r) {
        float4 dn4 = *(float4*)&su[ldn[r]];
        float urr = __shfl_down(u1v[r][0], 1, 64);
        if (lane == 63) urr = su[lrt[r]];
        float dn[4] = {dn4.x, dn4.y, dn4.z, dn4.w};
        H2x4 w;
#pragma unroll
        for (int e = 0; e < 4; ++e) {
            float uc = u1v[r][e];
            float gx = dn[e] - uc;
            float rt = (e == 3) ? urr : u1v[r][e + 1];
            float gy = (gj0a[r] + e < WW - 1) ? (rt - uc) : 0.f;
            __half2 g = __float22half2_rn(make_float2(gx, gy));
            w.h2[e] = clamp1h2(__hfma2(g, tau2, c2[r][e]));
        }
        if (wr[r]) *(float4*)&sp1[lb[r]] = w.f4;
    }
    __syncthreads();

    // out = x - c*div(p50) on interior
#pragma unroll
    for (int r = 0; r < 2; ++r) {
        int slot = tid + 256 * r;
        int ir = slot >> 4, icc = slot & 15;
        int er = ir + 2, ec = icc * 4 + 4;
        int l  = er * ECC + ec;
        int gi = r0 + ir, gj = c0 + icc * 4;

        H2x4 pc_; pc_.f4 = *(float4*)&sp1[l];
        H2x4 pu_; pu_.f4 = *(float4*)&sp1[l - ECC];
        __half2 plf = shfl_up_h2(pc_.h2[3]);
        if ((tid & 15) == 0) plf = sp1[l - 1];

        float4 xr4 = *(const float4*)(x + (size_t)gi * WW + gj);
        float xv[4] = {xr4.x, xr4.y, xr4.z, xr4.w};
        float o[4];
#pragma unroll
        for (int e = 0; e < 4; ++e) {
            __half2 cc = pc_.h2[e];
            __half2 le = (e == 0) ? plf : pc_.h2[e - 1];
            float dx = __low2float(pu_.h2[e]) - __low2float(cc);
            dx = (gi > 0) ? dx : 0.f;
            float dy = __high2float(le) - __high2float(cc);
            dy = (gj + e > 0) ? dy : 0.f;
            o[e] = xv[e] - C_LAM * (dx + dy);
        }
        *(float4*)(out + (size_t)gi * WW + gj) = make_float4(o[0], o[1], o[2], o[3]);
    }
}

extern "C" void kernel_launch(void* const* d_in, const int* in_sizes, int n_in,
                              void* d_out, int out_size, void* d_ws, size_t ws_size,
                              hipStream_t stream)
{
    const float* x = (const float*)d_in[0];
    float* out = (float*)d_out;
    const size_t N = (size_t)HH * (size_t)WW;

    // ws layout: pA (64 MiB) | pB (64 MiB) | x_h (32 MiB)
    __half2* pA = (__half2*)d_ws;
    __half2* pB = pA + N;
    __half*  xh = (__half*)(pB + N);

    dim3 b1(BX, BY), g1(WW / TILE_W, HH / BY);
    dim3 b8(256),    g8(WW / TW8, HH / TH8);
    dim3 bL(256),    gL(WW / TW2, HH / TH2);

    tv_first<<<g1, b1, 0, stream>>>(x, pA, xh);              // iter 1
    __half2 *pin = pA, *pout = pB;
    for (int p = 0; p < 6; ++p) {                            // iters 2..49 (6x8)
        tv_iter8<<<g8, b8, 0, stream>>>(xh, pin, pout);
        __half2* t = pin; pin = pout; pout = t;
    }
    tv_last<<<gL, bL, 0, stream>>>(xh, x, pin, out);         // iter 50 + output
}

// Round 13
// 511.035 us; speedup vs baseline: 2.2837x; 1.1251x over previous
//
#include <hip/hip_runtime.h>
#include <hip/hip_fp16.h>

#define HH 4096
#define WW 4096

constexpr float C_LAM = 0.1f;   // ALPHA * LAMDA
constexpr float TAU_F = 0.25f;

// ---- first-iteration kernel geometry ----
#define BX 64
#define BY 8
#define VEC 4
#define TILE_W (BX * VEC)       // 256 cols per block

// ---- tv_last (2-ring) geometry ----
#define TW2 64
#define TH2 32
#define ERR 36
#define ECC 72
#define NCH (ECC / 4)
#define NSL (ERR * NCH)         // 648
#define LSZ (ERR * ECC)         // 2592

// ---- tv_iter8 (8-step, register-strip) geometry ----
// Each thread owns 4 rows x 8 px in REGISTERS. LDS holds only strip-boundary
// rows (px row3 / u row0) and packed chunk-edge columns (py7 / u0, 4 rows in
// one b64). Per iter per thread: 8 LDS instrs instead of 28 (R12 was
// LDS-issue-bound: 28 x 7cy x 8 iters x 128 waves/CU ~= the measured 94 us).
#define TH8 32                  // interior rows
#define TW8 64                  // interior cols
#define XC8 80                  // extended cols [c0-8, c0+71]
#define NS8 12                  // 4-row strips over 48 extended rows
#define NQ8 10                  // 8-px chunks per row
#define NT8 120                 // active threads = NS8*NQ8

typedef float    __attribute__((ext_vector_type(4))) f32x4_t;
typedef float    __attribute__((ext_vector_type(2))) f32x2_t;
typedef unsigned __attribute__((ext_vector_type(2))) u32x2_t;

union H2x4 { float4 f4; f32x4_t v4; __half2 h2[4]; unsigned u32[4]; };
union H2x2 { float2 f2; f32x2_t v2; __half2 h2[2]; unsigned u32[2]; };
union H2U  { __half2 h; unsigned int u; };

__device__ __forceinline__ float clip1(float v) {
    return fminf(1.0f, fmaxf(-1.0f, v));
}

__device__ __forceinline__ unsigned h2u(__half2 h) { H2U a; a.h = h; return a.u; }
__device__ __forceinline__ __half2  u2h(unsigned u){ H2U a; a.u = u; return a.h; }

// v_perm_b32: result bytes select from {a(hi):b(lo)}; sel byte i in 0-3 -> b, 4-7 -> a
__device__ __forceinline__ __half2 permh(__half2 a, __half2 b, unsigned sel) {
    unsigned d;
    asm("v_perm_b32 %0, %1, %2, %3" : "=v"(d) : "v"(h2u(a)), "v"(h2u(b)), "v"(sel));
    return u2h(d);
}
__device__ __forceinline__ __half2 andh(__half2 v, unsigned m) { return u2h(h2u(v) & m); }

// packed clamp to [-1,1] (no __hmax2/__hmin2 in ROCm 7.2 headers)
__device__ __forceinline__ __half2 clamp1h2(__half2 v) {
    H2U a; a.h = v;
    unsigned int lo = 0xBC00BC00u;   // (-1, -1) fp16
    unsigned int hi = 0x3C003C00u;   // (+1, +1) fp16
    unsigned int t, r;
    asm("v_pk_max_f16 %0, %1, %2" : "=v"(t) : "v"(a.u), "v"(lo));
    asm("v_pk_min_f16 %0, %1, %2" : "=v"(r) : "v"(t),   "v"(hi));
    H2U b; b.u = r;
    return b.h;
}

__device__ __forceinline__ __half2 shfl_up_h2(__half2 v) {
    H2U a; a.h = v;
    int s = __shfl_up((int)a.u, 1, 64);
    H2U b; b.u = (unsigned)s;
    return b.h;
}

// (hi:lo) >> 16, as __half2: result = (lo.hi, hi.lo)
__device__ __forceinline__ __half2 align16(__half2 hi, __half2 lo) {
    H2U a, b, d;
    a.h = hi; b.h = lo;
    asm("v_alignbit_b32 %0, %1, %2, 16" : "=v"(d.u) : "v"(a.u), "v"(b.u));
    return d.h;
}

// iteration 0 (p=0 -> u=x):  p = clip(tau * grad(x)); also emits x_h = fp16(x)
__global__ __launch_bounds__(512) void tv_first(const float* __restrict__ x,
                                                __half2* __restrict__ po,
                                                __half* __restrict__ xh)
{
    const int tx = threadIdx.x, ty = threadIdx.y;
    const int i = blockIdx.y * BY + ty;
    const int j = blockIdx.x * TILE_W + tx * VEC;
    const size_t idx = (size_t)i * WW + j;

    float4 xc4 = *(const float4*)(x + idx);
    float4 xd4 = make_float4(0.f, 0.f, 0.f, 0.f);
    if (i < HH - 1) xd4 = *(const float4*)(x + idx + WW);

    float c[4] = {xc4.x, xc4.y, xc4.z, xc4.w};
    float d[4] = {xd4.x, xd4.y, xd4.z, xd4.w};

    float xr = __shfl_down(c[0], 1, 64);
    if (tx == BX - 1 && j + VEC < WW) xr = x[idx + VEC];

    H2x4 o;
#pragma unroll
    for (int e = 0; e < 4; ++e) {
        float gx = (i < HH - 1) ? (d[e] - c[e]) : 0.f;
        float rn = (e < 3) ? c[e + 1] : xr;
        float gy = (j + e < WW - 1) ? (rn - c[e]) : 0.f;
        o.h2[e] = __floats2half2_rn(clip1(TAU_F * gx), clip1(TAU_F * gy));
    }
    *(float4*)(po + idx) = o.f4;

    H2x2 xs;
    xs.h2[0] = __floats2half2_rn(c[0], c[1]);
    xs.h2[1] = __floats2half2_rn(c[2], c[3]);
    *(float2*)(xh + idx) = xs.f2;
}

// -------- eight fused Chambolle steps, register-strip decomposition --------
template<bool EDGE>
__device__ __forceinline__ void iter8_body(const __half* __restrict__ xh,
                                           const __half2* __restrict__ pi,
                                           __half2* __restrict__ po,
                                           __half* pxB, __half* uT,
                                           unsigned* pyE, unsigned* uE)
{
    const int tid = threadIdx.x;
    const bool act = (tid < NT8);
    const int t = act ? tid : (NT8 - 1);
    const int s = t / NQ8;
    const int q = t - s * NQ8;
    const int r0 = blockIdx.y * TH8, c0 = blockIdx.x * TW8;
    const int gi0 = r0 - 8 + 4 * s;              // global row of strip row 0
    const int gj0 = c0 - 8 + 8 * q;              // global col of chunk elem 0
    const int gjc = EDGE ? min(max(gj0, 0), WW - 8) : gj0;

    const int lB  = s * XC8 + 8 * q;             // own boundary-row slot
    const int lBu = ((s > 0) ? (s - 1) : 0) * XC8 + 8 * q;
    const int lBd = ((s < NS8 - 1) ? (s + 1) : s) * XC8 + 8 * q;
    const int eO = t * 2;                        // packed edge (u32 index)
    const int eL = ((q > 0) ? (t - 1) : t) * 2;
    const int eR = ((q < NQ8 - 1) ? (t + 1) : t) * 2;
    const bool wout = act && (s >= 2) && (s <= 9) && (q >= 1) && (q <= 8);

    unsigned mdy = 0xFFFFFFFFu, mgy = 0xFFFFFFFFu;
    if (EDGE) {
        if (gj0 == 0)      mdy = 0xFFFF0000u;    // zero dy at global col 0
        if (gj0 + 8 == WW) mgy = 0x0000FFFFu;    // zero gy at global col WW-1
    }

    const __half2 tau2 = __float2half2_rn(TAU_F);
    const __half2 nC2  = __float2half2_rn(-C_LAM);
    const unsigned SEL0 = 0x05040100u;   // (b.lo16, a.lo16)
    const unsigned SELH = 0x07060302u;   // (b.hi16, a.hi16)
    const unsigned SELM = 0x05040302u;   // (b.hi16, a.lo16)

    __half2 X[4][4], Y[4][4], XHr[4][4], U[4][4];

    // ---- stage A: load interleaved p + xh; deinterleave into registers ----
#pragma unroll
    for (int k = 0; k < 4; ++k) {
        int gik = gi0 + k;
        if (EDGE) gik = min(max(gik, 0), HH - 1);
        const size_t go = (size_t)gik * WW + gjc;
        H2x4 v0; v0.v4 = *(const f32x4_t*)(pi + go);
        H2x4 v1; v1.v4 = *(const f32x4_t*)(pi + go + 4);
        H2x4 xv; xv.v4 = *(const f32x4_t*)(xh + go);
        X[k][0] = permh(v0.h2[1], v0.h2[0], SEL0);
        Y[k][0] = permh(v0.h2[1], v0.h2[0], SELH);
        X[k][1] = permh(v0.h2[3], v0.h2[2], SEL0);
        Y[k][1] = permh(v0.h2[3], v0.h2[2], SELH);
        X[k][2] = permh(v1.h2[1], v1.h2[0], SEL0);
        Y[k][2] = permh(v1.h2[1], v1.h2[0], SELH);
        X[k][3] = permh(v1.h2[3], v1.h2[2], SEL0);
        Y[k][3] = permh(v1.h2[3], v1.h2[2], SELH);
#pragma unroll
        for (int m = 0; m < 4; ++m) XHr[k][m] = xv.h2[m];
    }

#pragma unroll
    for (int it = 0; it < 8; ++it) {
        const bool last = (it == 7);

        // ---- publish p boundaries (px row3 full; py7 edges packed) ----
        if (act) {
            H2x4 w;
#pragma unroll
            for (int m = 0; m < 4; ++m) w.h2[m] = X[3][m];
            *(f32x4_t*)(pxB + lB) = w.v4;
            u32x2_t e;
            e.x = h2u(permh(Y[1][3], Y[0][3], SELH));   // (py7 r0, py7 r1)
            e.y = h2u(permh(Y[3][3], Y[2][3], SELH));   // (py7 r2, py7 r3)
            *(u32x2_t*)(pyE + eO) = e;
        }
        __syncthreads();

        // ---- u-stage: u = xh - C*div(p) ----
        {
            H2x4 pu; pu.v4 = *(const f32x4_t*)(pxB + lBu);
            u32x2_t Lp = *(const u32x2_t*)(pyE + eL);
            const __half2 L0 = u2h(Lp.x), L1 = u2h(Lp.y);
#pragma unroll
            for (int k = 0; k < 4; ++k) {
                __half2 dx[4], zm[4], dy[4];
#pragma unroll
                for (int m = 0; m < 4; ++m)
                    dx[m] = __hsub2((k == 0) ? pu.h2[m] : X[k - 1][m], X[k][m]);
                if (EDGE && !(gi0 + k > 0)) {
#pragma unroll
                    for (int m = 0; m < 4; ++m) dx[m] = u2h(0u);
                }
                zm[0] = (k == 0) ? permh(Y[k][0], L0, SEL0)
                      : (k == 1) ? permh(Y[k][0], L0, SELM)
                      : (k == 2) ? permh(Y[k][0], L1, SEL0)
                                 : permh(Y[k][0], L1, SELM);
                zm[1] = align16(Y[k][1], Y[k][0]);
                zm[2] = align16(Y[k][2], Y[k][1]);
                zm[3] = align16(Y[k][3], Y[k][2]);
#pragma unroll
                for (int m = 0; m < 4; ++m) dy[m] = __hsub2(zm[m], Y[k][m]);
                if (EDGE) dy[0] = andh(dy[0], mdy);
#pragma unroll
                for (int m = 0; m < 4; ++m)
                    U[k][m] = __hfma2(__hadd2(dx[m], dy[m]), nC2, XHr[k][m]);
            }
            if (act) {
                H2x4 w;
#pragma unroll
                for (int m = 0; m < 4; ++m) w.h2[m] = U[0][m];
                *(f32x4_t*)(uT + lB) = w.v4;
                u32x2_t e;
                e.x = h2u(permh(U[1][0], U[0][0], SEL0));   // (u0 r0, u0 r1)
                e.y = h2u(permh(U[3][0], U[2][0], SEL0));   // (u0 r2, u0 r3)
                *(u32x2_t*)(uE + eO) = e;
            }
        }
        __syncthreads();

        // ---- p-stage: p = clip(p + tau*grad(u)) ----
        {
            H2x4 ud; ud.v4 = *(const f32x4_t*)(uT + lBd);
            u32x2_t Rp = *(const u32x2_t*)(uE + eR);
            const __half2 R0 = u2h(Rp.x), R1 = u2h(Rp.y);
#pragma unroll
            for (int k = 0; k < 4; ++k) {
                __half2 gx[4], zp[4], gy[4];
#pragma unroll
                for (int m = 0; m < 4; ++m)
                    gx[m] = __hsub2((k == 3) ? ud.h2[m] : U[k + 1][m], U[k][m]);
                if (EDGE && !(gi0 + k < HH - 1)) {
#pragma unroll
                    for (int m = 0; m < 4; ++m) gx[m] = u2h(0u);
                }
                zp[0] = align16(U[k][1], U[k][0]);
                zp[1] = align16(U[k][2], U[k][1]);
                zp[2] = align16(U[k][3], U[k][2]);
                zp[3] = (k == 0) ? permh(R0, U[k][3], SELM)   // (u7, uR0 r0)
                      : (k == 1) ? permh(R0, U[k][3], SELH)
                      : (k == 2) ? permh(R1, U[k][3], SELM)
                                 : permh(R1, U[k][3], SELH);
#pragma unroll
                for (int m = 0; m < 4; ++m) gy[m] = __hsub2(zp[m], U[k][m]);
                if (EDGE) gy[3] = andh(gy[3], mgy);
#pragma unroll
                for (int m = 0; m < 4; ++m) {
                    X[k][m] = clamp1h2(__hfma2(gx[m], tau2, X[k][m]));
                    Y[k][m] = clamp1h2(__hfma2(gy[m], tau2, Y[k][m]));
                }
            }
        }

        if (last && wout) {
#pragma unroll
            for (int k = 0; k < 4; ++k) {
                const size_t go = (size_t)(gi0 + k) * WW + gj0;
                H2x4 w0, w1;
                w0.h2[0] = permh(Y[k][0], X[k][0], SEL0);   // (px0, py0)
                w0.h2[1] = permh(Y[k][0], X[k][0], SELH);   // (px1, py1)
                w0.h2[2] = permh(Y[k][1], X[k][1], SEL0);
                w0.h2[3] = permh(Y[k][1], X[k][1], SELH);
                w1.h2[0] = permh(Y[k][2], X[k][2], SEL0);
                w1.h2[1] = permh(Y[k][2], X[k][2], SELH);
                w1.h2[2] = permh(Y[k][3], X[k][3], SEL0);
                w1.h2[3] = permh(Y[k][3], X[k][3], SELH);
                *(f32x4_t*)(po + go)     = w0.v4;
                *(f32x4_t*)(po + go + 4) = w1.v4;
            }
        }
    }
}

__global__ __launch_bounds__(128) void tv_iter8(const __half* __restrict__ xh,
                                                const __half2* __restrict__ pi,
                                                __half2* __restrict__ po)
{
    __shared__ __align__(16) __half   pxB[NS8 * XC8];
    __shared__ __align__(16) __half   uT [NS8 * XC8];
    __shared__ __align__(8)  unsigned pyE[NT8 * 2];
    __shared__ __align__(8)  unsigned uE [NT8 * 2];

    const bool edge = (blockIdx.x == 0) || (blockIdx.x == gridDim.x - 1) ||
                      (blockIdx.y == 0) || (blockIdx.y == gridDim.y - 1);
    if (!edge) iter8_body<false>(xh, pi, po, pxB, uT, pyE, uE);
    else       iter8_body<true >(xh, pi, po, pxB, uT, pyE, uE);
}

// -------- final: one more p-update (p49 -> p50) fused with the output --------
__global__ __launch_bounds__(256) void tv_last(const __half* __restrict__ xh,
                                               const float* __restrict__ x,
                                               const __half2* __restrict__ pi,
                                               float* __restrict__ out)
{
    __shared__ __half2 sp0[LSZ];
    __shared__ __half2 sp1[LSZ];
    __shared__ float   su [LSZ];

    const int tid  = threadIdx.x;
    const int lane = tid & 63;
    const int r0 = blockIdx.y * TH2;
    const int c0 = blockIdx.x * TW2;
    const __half2 tau2 = __float2half2_rn(TAU_F);

    int lb[3], lup[3], llf[3], ldn[3], lrt[3], gj0a[3], gofs[3];
    bool wr[3];
#pragma unroll
    for (int r = 0; r < 3; ++r) {
        int slot = tid + 256 * r;
        wr[r] = (slot < NSL);
        if (slot >= NSL) slot = NSL - 1;
        int cr = slot / NCH;
        int cc = slot - cr * NCH;
        int gi  = r0 - 2 + cr;
        int gj0 = c0 - 4 + cc * 4;
        int gic = min(max(gi, 0), HH - 1);
        int gjc = min(max(gj0, 0), WW - 4);
        gofs[r] = gic * WW + gjc;
        int l   = cr * ECC + cc * 4;
        lb[r]  = l;
        lup[r] = (cr > 0) ? l - ECC : l;
        llf[r] = (l > 0) ? l - 1 : 0;
        ldn[r] = (cr < ERR - 1) ? l + ECC : l;
        lrt[r] = min(l + 4, LSZ - 1);
        gj0a[r] = gj0;
    }

    __half2 c2[3][4];
    H2x2    xc[3];
#pragma unroll
    for (int r = 0; r < 3; ++r) {
        H2x4 v; v.f4 = *(const float4*)(pi + gofs[r]);
        xc[r].f2    = *(const float2*)(xh + gofs[r]);
        if (wr[r]) *(float4*)&sp0[lb[r]] = v.f4;
        c2[r][0] = v.h2[0]; c2[r][1] = v.h2[1];
        c2[r][2] = v.h2[2]; c2[r][3] = v.h2[3];
    }
    __syncthreads();

    float u1v[3][4];
#pragma unroll
    for (int r = 0; r < 3; ++r) {
        H2x4 up; up.f4 = *(float4*)&sp0[lup[r]];
        __half2 lf = shfl_up_h2(c2[r][3]);
        if (lane == 0) lf = sp0[llf[r]];
        float xs[4] = {__low2float(xc[r].h2[0]), __high2float(xc[r].h2[0]),
                       __low2float(xc[r].h2[1]), __high2float(xc[r].h2[1])};
        float4 w;
        float* wp = &w.x;
#pragma unroll
        for (int e = 0; e < 4; ++e) {
            __half2 cc = c2[r][e];
            __half2 le = (e == 0) ? lf : c2[r][e - 1];
            float dx = __low2float(up.h2[e]) - __low2float(cc);
            float dy = __high2float(le) - __high2float(cc);
            dy = (gj0a[r] + e > 0) ? dy : 0.f;
            float u = xs[e] - C_LAM * (dx + dy);
            u1v[r][e] = u;
            wp[e] = u;
        }
        if (wr[r]) *(float4*)&su[lb[r]] = w;
    }
    __syncthreads();

#pragma unroll
    for (int r = 0; r < 3; ++r) {
        float4 dn4 = *(float4*)&su[ldn[r]];
        float urr = __shfl_down(u1v[r][0], 1, 64);
        if (lane == 63) urr = su[lrt[r]];
        float dn[4] = {dn4.x, dn4.y, dn4.z, dn4.w};
        H2x4 w;
#pragma unroll
        for (int e = 0; e < 4; ++e) {
            float uc = u1v[r][e];
            float gx = dn[e] - uc;
            float rt = (e == 3) ? urr : u1v[r][e + 1];
            float gy = (gj0a[r] + e < WW - 1) ? (rt - uc) : 0.f;
            __half2 g = __float22half2_rn(make_float2(gx, gy));
            w.h2[e] = clamp1h2(__hfma2(g, tau2, c2[r][e]));
        }
        if (wr[r]) *(float4*)&sp1[lb[r]] = w.f4;
    }
    __syncthreads();

    // out = x - c*div(p50) on interior
#pragma unroll
    for (int r = 0; r < 2; ++r) {
        int slot = tid + 256 * r;
        int ir = slot >> 4, icc = slot & 15;
        int er = ir + 2, ec = icc * 4 + 4;
        int l  = er * ECC + ec;
        int gi = r0 + ir, gj = c0 + icc * 4;

        H2x4 pc_; pc_.f4 = *(float4*)&sp1[l];
        H2x4 pu_; pu_.f4 = *(float4*)&sp1[l - ECC];
        __half2 plf = shfl_up_h2(pc_.h2[3]);
        if ((tid & 15) == 0) plf = sp1[l - 1];

        float4 xr4 = *(const float4*)(x + (size_t)gi * WW + gj);
        float xv[4] = {xr4.x, xr4.y, xr4.z, xr4.w};
        float o[4];
#pragma unroll
        for (int e = 0; e < 4; ++e) {
            __half2 cc = pc_.h2[e];
            __half2 le = (e == 0) ? plf : pc_.h2[e - 1];
            float dx = __low2float(pu_.h2[e]) - __low2float(cc);
            dx = (gi > 0) ? dx : 0.f;
            float dy = __high2float(le) - __high2float(cc);
            dy = (gj + e > 0) ? dy : 0.f;
            o[e] = xv[e] - C_LAM * (dx + dy);
        }
        *(float4*)(out + (size_t)gi * WW + gj) = make_float4(o[0], o[1], o[2], o[3]);
    }
}

extern "C" void kernel_launch(void* const* d_in, const int* in_sizes, int n_in,
                              void* d_out, int out_size, void* d_ws, size_t ws_size,
                              hipStream_t stream)
{
    const float* x = (const float*)d_in[0];
    float* out = (float*)d_out;
    const size_t N = (size_t)HH * (size_t)WW;

    // ws layout: pA (64 MiB) | pB (64 MiB) | x_h (32 MiB)
    __half2* pA = (__half2*)d_ws;
    __half2* pB = pA + N;
    __half*  xh = (__half*)(pB + N);

    dim3 b1(BX, BY), g1(WW / TILE_W, HH / BY);
    dim3 b8(128),    g8(WW / TW8, HH / TH8);
    dim3 bL(256),    gL(WW / TW2, HH / TH2);

    tv_first<<<g1, b1, 0, stream>>>(x, pA, xh);              // iter 1
    __half2 *pin = pA, *pout = pB;
    for (int p = 0; p < 6; ++p) {                            // iters 2..49 (6x8)
        tv_iter8<<<g8, b8, 0, stream>>>(xh, pin, pout);
        __half2* t = pin; pin = pout; pout = t;
    }
    tv_last<<<gL, bL, 0, stream>>>(xh, x, pin, out);         // iter 50 + output
}